// Round 3
// baseline (5292.060 us; speedup 1.0000x reference)
//
#include <hip/hip_runtime.h>

typedef unsigned int u32;
typedef unsigned short u16;
typedef short s16x8 __attribute__((ext_vector_type(8)));
typedef short s16x4 __attribute__((ext_vector_type(4)));
typedef float f32x4 __attribute__((ext_vector_type(4)));

namespace {
constexpr int kB = 16384, kL = 20;

// packed split-bf16 weights in d_ws (u16 elems). per (kt,n): hi[32] then lo[32]
constexpr int OFF_A1 = 0;                      // 128x256
constexpr int OFF_A2 = OFF_A1 + 128 * 256 * 2; // 256x256
constexpr int OFF_M1 = OFF_A2 + 256 * 256 * 2; // 128x256
constexpr int OFF_M2 = OFF_M1 + 128 * 256 * 2; // 256x256
constexpr int OFF_M3 = OFF_M2 + 256 * 256 * 2; // 256x64
constexpr int OFF_U1 = OFF_M3 + 256 * 64 * 2;  // 64x64
constexpr int OFF_U2T = OFF_U1 + 64 * 64 * 2;  // 64x64 (uW2 rows 0..63)
constexpr int OFF_U2B = OFF_U2T + 64 * 64 * 2; // 64x64 (uW2 rows 64..127)
constexpr int OFF_U3 = OFF_U2B + 64 * 64 * 2;  // 64x64
constexpr int PACK_ELEMS = OFF_U3 + 64 * 64 * 2; // 458752 u16 = 917504 B
constexpr size_t PT_OFF = (size_t)PACK_ELEMS;    // u16 index; byte 917504 (256-aligned)
constexpr size_t WS_NEED = PT_OFF * 2 + (size_t)kB * kL * 64 * 4; // ~84.8 MB

__device__ __forceinline__ u16 f2bf(float x) {
  u32 b = __builtin_bit_cast(u32, x);
  b += 0x7FFFu + ((b >> 16) & 1u);
  return (u16)(b >> 16);
}
__device__ __forceinline__ float bf2f(u16 h) {
  return __builtin_bit_cast(float, (u32)h << 16);
}
__device__ __forceinline__ void split2(float x, u16& hi, u16& lo) {
  hi = f2bf(x);
  lo = f2bf(x - bf2f(hi));
}
__device__ __forceinline__ float wsum64(float v) {
  #pragma unroll
  for (int off = 32; off > 0; off >>= 1) v += __shfl_xor(v, off, 64);
  return v;
}
__device__ __forceinline__ f32x4 mfma16(s16x8 a, s16x8 b, f32x4 c) {
  return __builtin_amdgcn_mfma_f32_16x16x32_bf16(a, b, c, 0, 0, 0);
}
__device__ __forceinline__ s16x8 ldsf(const u16* p) {
  return *reinterpret_cast<const s16x8*>(p);
}

// C-tile accumulate: A from swizzled LDS planes, B from packed global.
// rowA = mh*16 + r15 (A-operand row); c0 = lane's column (tilebase + r15).
template <int K, int LD, int N, int NT>
__device__ __forceinline__ void mm_acc(
    const u16* __restrict__ AH, const u16* __restrict__ AL,
    const u16* __restrict__ Bp, int rowA, int c0, int g, f32x4 (&acc)[NT]) {
  #pragma unroll
  for (int kt = 0; kt < K / 32; ++kt) {
    const int off = (rowA * LD + kt * 32 + g * 8) ^ ((rowA & 7) << 3);
    s16x8 ah = ldsf(AH + off);
    s16x8 al = ldsf(AL + off);
    #pragma unroll
    for (int nt = 0; nt < NT; ++nt) {
      const u16* bp = Bp + (kt * N + c0 + nt * 16) * 64 + g * 8;
      s16x8 bh = *reinterpret_cast<const s16x8*>(bp);
      s16x8 bl = *reinterpret_cast<const s16x8*>(bp + 32);
      acc[nt] = mfma16(ah, bh, acc[nt]);
      acc[nt] = mfma16(al, bh, acc[nt]);
      acc[nt] = mfma16(ah, bl, acc[nt]);
    }
  }
}

__device__ __forceinline__ void epi_relu(
    const f32x4 (&acc)[4], const float* __restrict__ bias,
    u16* __restrict__ OH, u16* __restrict__ OL, int mh, int nq, int r15, int g) {
  #pragma unroll
  for (int nt = 0; nt < 4; ++nt) {
    const int col = nq * 64 + nt * 16 + r15;
    const float bb = bias[col];
    #pragma unroll
    for (int i = 0; i < 4; ++i) {
      const int row = mh * 16 + g * 4 + i;
      float vv = fmaxf(acc[nt][i] + bb, 0.f);
      u16 h, l;
      split2(vv, h, l);
      const int o = (row * 256 + col) ^ ((row & 7) << 3);
      OH[o] = h;
      OL[o] = l;
    }
  }
}
}  // namespace

// ---------------- prep: pack weights as split-bf16 frag layout ----------------
__global__ __launch_bounds__(256) void prep_kernel(
    const float* __restrict__ aW1, const float* __restrict__ aW2,
    const float* __restrict__ mW1, const float* __restrict__ mW2,
    const float* __restrict__ mW3, const float* __restrict__ uW1,
    const float* __restrict__ uW2, const float* __restrict__ uW3,
    u16* __restrict__ ws, int nl) {
  const float* Ws[9] = {aW1, aW2, mW1, mW2, mW3, uW1, uW2, uW2 + 64 * 64, uW3};
  const int Ns[9] = {256, 256, 256, 256, 64, 64, 64, 64, 64};
  const int dst[9] = {OFF_A1, OFF_A2, OFF_M1, OFF_M2, OFF_M3, OFF_U1, OFF_U2T, OFF_U2B, OFF_U3};
  const int cnt[9] = {32768, 65536, 32768, 65536, 16384, 4096, 4096, 4096, 4096};
  const int total = (nl == 9) ? 229376 : 212992;
  for (int e = blockIdx.x * 256 + threadIdx.x; e < total; e += gridDim.x * 256) {
    int l = 0, base = 0;
    while (e - base >= cnt[l]) { base += cnt[l]; ++l; }
    const int s = e - base, N = Ns[l];
    const int k = s / N, n = s % N;
    u16 hi, lo;
    split2(Ws[l][s], hi, lo);
    const int ob = dst[l] + ((k >> 5) * N + n) * 64 + (k & 31);
    ws[ob] = hi;
    ws[ob + 32] = lo;
  }
}

// ---------------- K1: batched u1 + P2 = tanh(h)@uW2top + ub2 ----------------
__global__ __launch_bounds__(512, 2) void k1_kernel(
    const float* __restrict__ state, const float* __restrict__ ub1,
    const float* __restrict__ ub2, const u16* __restrict__ wsp,
    float* __restrict__ pt) {
  __shared__ __align__(16) u16 xH[32 * 64], xL[32 * 64];
  __shared__ __align__(16) u16 thH[32 * 64], thL[32 * 64];
  __shared__ __align__(16) float smc[32 * 64];
  const int tid = threadIdx.x;
  const int lane = tid & 63, w = tid >> 6;
  const int r15 = lane & 15, g = lane >> 4;
  const int mh = w >> 2, nq = w & 3;
  const int rowA = mh * 16 + r15;
  const size_t itemBase = (size_t)blockIdx.x * 32;
  {  // stage + split state
    const int r = tid >> 4, p = tid & 15;
    f32x4 v = *reinterpret_cast<const f32x4*>(state + (itemBase + r) * 64 + p * 4);
    s16x4 hh, ll;
    #pragma unroll
    for (int j = 0; j < 4; ++j) { u16 h, l; split2(v[j], h, l); hh[j] = (short)h; ll[j] = (short)l; }
    const int o = (r * 64 + p * 4) ^ ((r & 7) << 3);
    *reinterpret_cast<s16x4*>(xH + o) = hh;
    *reinterpret_cast<s16x4*>(xL + o) = ll;
  }
  __syncthreads();
  {  // u1 raw
    const int c = nq * 16 + r15;
    f32x4 acc[1] = {{0.f, 0.f, 0.f, 0.f}};
    mm_acc<64, 64, 64, 1>(xH, xL, wsp + OFF_U1, rowA, c, g, acc);
    const float bb = ub1[c];
    #pragma unroll
    for (int i = 0; i < 4; ++i) smc[(mh * 16 + g * 4 + i) * 64 + c] = acc[0][i] + bb;
  }
  __syncthreads();
  {  // normalize + tanh -> th planes
    const int r = tid >> 4, p = tid & 15;
    f32x4 v = *reinterpret_cast<const f32x4*>(smc + r * 64 + p * 4);
    float ss = v[0] * v[0] + v[1] * v[1] + v[2] * v[2] + v[3] * v[3];
    #pragma unroll
    for (int off = 8; off >= 1; off >>= 1) ss += __shfl_xor(ss, off, 64);
    const float inv = 1.f / fmaxf(sqrtf(ss), 1e-12f);
    s16x4 hh, ll;
    #pragma unroll
    for (int j = 0; j < 4; ++j) {
      u16 h, l;
      split2(tanhf(v[j] * inv), h, l);
      hh[j] = (short)h;
      ll[j] = (short)l;
    }
    const int o = (r * 64 + p * 4) ^ ((r & 7) << 3);
    *reinterpret_cast<s16x4*>(thH + o) = hh;
    *reinterpret_cast<s16x4*>(thL + o) = ll;
  }
  __syncthreads();
  {  // P2 = th @ U2T + ub2
    const int c = nq * 16 + r15;
    f32x4 acc[1] = {{0.f, 0.f, 0.f, 0.f}};
    mm_acc<64, 64, 64, 1>(thH, thL, wsp + OFF_U2T, rowA, c, g, acc);
    const float bb = ub2[c];
    #pragma unroll
    for (int i = 0; i < 4; ++i)
      pt[(itemBase + mh * 16 + g * 4 + i) * 64 + c] = acc[0][i] + bb;
  }
}

// ---------------- K24: fused bottom-up + top-down recurrences ----------------
__global__ __launch_bounds__(512, 2) void k24_kernel(
    const float* __restrict__ ub3, const float* __restrict__ ab1,
    const float* __restrict__ ab2, const float* __restrict__ aW3,
    const float* __restrict__ ab3, const float* __restrict__ mb1,
    const float* __restrict__ mb2, const float* __restrict__ mb3,
    const u16* __restrict__ wsp, float* __restrict__ pt,
    float* __restrict__ out) {
  __shared__ __align__(16) u16 xmH[32 * 128], xmL[32 * 128];
  __shared__ __align__(16) u16 b1H[32 * 256], b1L[32 * 256];
  __shared__ __align__(16) u16 b2H[32 * 256], b2L[32 * 256];
  __shared__ __align__(16) u16 tmH[32 * 64], tmL[32 * 64];
  __shared__ __align__(16) u16 h6H[32 * 64], h6L[32 * 64];
  __shared__ __align__(16) float smc[32 * 64];
  __shared__ float s_ab1[256], s_ab2[256], s_mb1[256], s_mb2[256], s_aw3[256];
  __shared__ float s_mb3[64], s_ub3[64];

  const int tid = threadIdx.x;
  const int w = tid >> 6, lane = tid & 63;
  const int r15 = lane & 15, g = lane >> 4;
  const int mh = w >> 2, nq = w & 3;
  const int rowA = mh * 16 + r15;
  const int rowBase = blockIdx.x * 32;

  if (tid < 256) {
    s_ab1[tid] = ab1[tid];
    s_ab2[tid] = ab2[tid];
    s_mb1[tid] = mb1[tid];
  } else {
    const int i = tid - 256;
    s_mb2[i] = mb2[i];
    s_aw3[i] = aW3[i];
    if (i < 64) { s_mb3[i] = mb3[i]; s_ub3[i] = ub3[i]; }
  }
  for (int i = tid; i < 32 * 64; i += 512) { tmH[i] = 0; tmL[i] = 0; }
  const float ab3v = ab3[0];
  __syncthreads();

  // ---- bottom-up: t = 19..0 ----
  for (int t = kL - 1; t >= 0; --t) {
    {  // pa: z = P2 + tm @ U2B ; h6 = tanh(z)
      const int c = nq * 16 + r15;
      float p2v[4];
      #pragma unroll
      for (int i = 0; i < 4; ++i)
        p2v[i] = pt[((size_t)(rowBase + mh * 16 + g * 4 + i) * kL + t) * 64 + c];
      f32x4 acc[1] = {{0.f, 0.f, 0.f, 0.f}};
      mm_acc<64, 64, 64, 1>(tmH, tmL, wsp + OFF_U2B, rowA, c, g, acc);
      #pragma unroll
      for (int i = 0; i < 4; ++i) {
        const int row = mh * 16 + g * 4 + i;
        u16 h, l;
        split2(tanhf(acc[0][i] + p2v[i]), h, l);
        const int o = (row * 64 + c) ^ ((row & 7) << 3);
        h6H[o] = h;
        h6L[o] = l;
      }
    }
    __syncthreads();
    {  // pb: u3 -> smc raw (+ub3)
      const int c = nq * 16 + r15;
      f32x4 acc[1] = {{0.f, 0.f, 0.f, 0.f}};
      mm_acc<64, 64, 64, 1>(h6H, h6L, wsp + OFF_U3, rowA, c, g, acc);
      const float bb = s_ub3[c];
      #pragma unroll
      for (int i = 0; i < 4; ++i) smc[(mh * 16 + g * 4 + i) * 64 + c] = acc[0][i] + bb;
    }
    __syncthreads();
    {  // pc: normalize + tanh -> tm planes + pt (overwrites consumed P2 slot)
      const int r = tid >> 4, p = tid & 15;
      f32x4 v = *reinterpret_cast<const f32x4*>(smc + r * 64 + p * 4);
      float ss = v[0] * v[0] + v[1] * v[1] + v[2] * v[2] + v[3] * v[3];
      #pragma unroll
      for (int off = 8; off >= 1; off >>= 1) ss += __shfl_xor(ss, off, 64);
      const float inv = 1.f / fmaxf(sqrtf(ss), 1e-12f);
      f32x4 tv;
      #pragma unroll
      for (int j = 0; j < 4; ++j) tv[j] = tanhf(v[j] * inv);
      *reinterpret_cast<f32x4*>(pt + ((size_t)(rowBase + r) * kL + t) * 64 + p * 4) = tv;
      s16x4 hh, ll;
      #pragma unroll
      for (int j = 0; j < 4; ++j) { u16 h, l; split2(tv[j], h, l); hh[j] = (short)h; ll[j] = (short)l; }
      const int o = (r * 64 + p * 4) ^ ((r & 7) << 3);
      *reinterpret_cast<s16x4*>(tmH + o) = hh;
      *reinterpret_cast<s16x4*>(tmL + o) = ll;
    }
    __syncthreads();
  }

  for (int i = tid; i < 32 * 64; i += 512) smc[i] = 0.f;  // mcur = 0
  __syncthreads();

  // ---- top-down: t = 0..19 ----
  for (int t = 0; t < kL; ++t) {
    {  // ph0: xm = [tanh(mu) | tanh(m)] planes
      const int r = tid >> 4, c8 = (tid & 15) * 8;
      float v[8];
      if (c8 < 64) {
        const float* src = pt + ((size_t)(rowBase + r) * kL + t) * 64 + c8;
        f32x4 a = *reinterpret_cast<const f32x4*>(src);
        f32x4 b = *reinterpret_cast<const f32x4*>(src + 4);
        v[0] = a[0]; v[1] = a[1]; v[2] = a[2]; v[3] = a[3];
        v[4] = b[0]; v[5] = b[1]; v[6] = b[2]; v[7] = b[3];
      } else {
        #pragma unroll
        for (int j = 0; j < 8; ++j) v[j] = tanhf(smc[r * 64 + c8 - 64 + j]);
      }
      s16x8 hh, ll;
      #pragma unroll
      for (int j = 0; j < 8; ++j) { u16 h, l; split2(v[j], h, l); hh[j] = (short)h; ll[j] = (short)l; }
      const int o = (r * 128 + c8) ^ ((r & 7) << 3);
      *reinterpret_cast<s16x8*>(xmH + o) = hh;
      *reinterpret_cast<s16x8*>(xmL + o) = ll;
    }
    __syncthreads();
    const int c0 = nq * 64 + r15;
    {  // ph1: A1
      f32x4 acc[4] = {};
      mm_acc<128, 128, 256, 4>(xmH, xmL, wsp + OFF_A1, rowA, c0, g, acc);
      epi_relu(acc, s_ab1, b1H, b1L, mh, nq, r15, g);
    }
    __syncthreads();
    {  // ph2: A2
      f32x4 acc[4] = {};
      mm_acc<256, 256, 256, 4>(b1H, b1L, wsp + OFF_A2, rowA, c0, g, acc);
      epi_relu(acc, s_ab2, b2H, b2L, mh, nq, r15, g);
    }
    __syncthreads();
    {  // ph3: M1 (xm -> b1) + A3 (b2 -> out)
      f32x4 acc[4] = {};
      mm_acc<128, 128, 256, 4>(xmH, xmL, wsp + OFF_M1, rowA, c0, g, acc);
      epi_relu(acc, s_mb1, b1H, b1L, mh, nq, r15, g);
      const int r = tid >> 4, p = tid & 15;
      const int o0 = (r * 256 + p * 16) ^ ((r & 7) << 3);
      const int o1 = (r * 256 + p * 16 + 8) ^ ((r & 7) << 3);
      s16x8 h0 = ldsf(b2H + o0), h1 = ldsf(b2H + o1);
      s16x8 l0 = ldsf(b2L + o0), l1 = ldsf(b2L + o1);
      float sum = 0.f;
      #pragma unroll
      for (int j = 0; j < 8; ++j) {
        sum += (bf2f((u16)h0[j]) + bf2f((u16)l0[j])) * s_aw3[p * 16 + j];
        sum += (bf2f((u16)h1[j]) + bf2f((u16)l1[j])) * s_aw3[p * 16 + 8 + j];
      }
      #pragma unroll
      for (int off = 8; off >= 1; off >>= 1) sum += __shfl_xor(sum, off, 64);
      if (p == 0) out[(size_t)(rowBase + r) * kL + t] = tanhf(sum + ab3v);
    }
    __syncthreads();
    {  // ph4: M2
      f32x4 acc[4] = {};
      mm_acc<256, 256, 256, 4>(b1H, b1L, wsp + OFF_M2, rowA, c0, g, acc);
      epi_relu(acc, s_mb2, b2H, b2L, mh, nq, r15, g);
    }
    __syncthreads();
    {  // ph5: M3 -> smc raw (+mb3)
      const int c = nq * 16 + r15;
      f32x4 acc[1] = {{0.f, 0.f, 0.f, 0.f}};
      mm_acc<256, 256, 64, 1>(b2H, b2L, wsp + OFF_M3, rowA, c, g, acc);
      const float bb = s_mb3[c];
      #pragma unroll
      for (int i = 0; i < 4; ++i) smc[(mh * 16 + g * 4 + i) * 64 + c] = acc[0][i] + bb;
    }
    __syncthreads();
    {  // ph6: normalize smc in place
      const int r = tid >> 4, p = tid & 15;
      f32x4 v = *reinterpret_cast<const f32x4*>(smc + r * 64 + p * 4);
      float ss = v[0] * v[0] + v[1] * v[1] + v[2] * v[2] + v[3] * v[3];
      #pragma unroll
      for (int off = 8; off >= 1; off >>= 1) ss += __shfl_xor(ss, off, 64);
      const float inv = 1.f / fmaxf(sqrtf(ss), 1e-12f);
      v[0] *= inv; v[1] *= inv; v[2] *= inv; v[3] *= inv;
      *reinterpret_cast<f32x4*>(smc + r * 64 + p * 4) = v;
    }
    __syncthreads();
  }
}

// ---------------- fallback: round-2 monolithic kernel (ws too small) ----------------
namespace {
constexpr int RPB_F = 16;
constexpr int NTHR_F = 512;
template <int K, int N, bool RELU>
__device__ __forceinline__ void mfma_layer_f(
    const u16* __restrict__ Ah, const u16* __restrict__ Al, const int lda,
    const u16* __restrict__ Bp, const float* __restrict__ bias,
    u16* __restrict__ Oh, u16* __restrict__ Ol, const int ldo,
    const int wv, const int r15, const int g) {
  constexpr int KT = K / 32;
  const int nt0 = wv * 2;
  if (nt0 >= N / 16) return;
  const int c0 = nt0 * 16 + r15;
  f32x4 acc0 = {0.f, 0.f, 0.f, 0.f}, acc1 = acc0;
  #pragma unroll
  for (int kt = 0; kt < KT; ++kt) {
    const int abase = r15 * lda + kt * 32 + g * 8;
    s16x8 ah = ldsf(Ah + abase), al = ldsf(Al + abase);
    const u16* b0 = Bp + (size_t)((kt * N + c0) * 2) * 32 + g * 8;
    const u16* b1 = Bp + (size_t)((kt * N + c0 + 16) * 2) * 32 + g * 8;
    s16x8 b0h = ldsf(b0), b0l = ldsf(b0 + 32);
    s16x8 b1h = ldsf(b1), b1l = ldsf(b1 + 32);
    acc0 = mfma16(ah, b0h, acc0); acc0 = mfma16(al, b0h, acc0); acc0 = mfma16(ah, b0l, acc0);
    acc1 = mfma16(ah, b1h, acc1); acc1 = mfma16(al, b1h, acc1); acc1 = mfma16(ah, b1l, acc1);
  }
  #pragma unroll
  for (int nt = 0; nt < 2; ++nt) {
    const int col = c0 + nt * 16;
    const float bb = bias[col];
    const f32x4 a = nt ? acc1 : acc0;
    #pragma unroll
    for (int i = 0; i < 4; ++i) {
      const int row = g * 4 + i;
      float v = a[i] + bb;
      if (RELU) v = fmaxf(v, 0.0f);
      u16 h, l;
      split2(v, h, l);
      Oh[row * ldo + col] = h;
      Ol[row * ldo + col] = l;
    }
  }
}
struct BU_F {
  float sW1[64][64];
  float sW2[128][64];
  float sW3[64][64];
  float bufX[RPB_F][132];
  float bufS[RPB_F][68];
};
struct TD_F {
  u16 xmH[RPB_F][136], xmL[RPB_F][136];
  u16 bAH[RPB_F][264], bAL[RPB_F][264];
  u16 bBH[RPB_F][264], bBL[RPB_F][264];
  float md[RPB_F][68];
};
}  // namespace

__global__ __launch_bounds__(NTHR_F) void actor_fallback_kernel(
    const float* __restrict__ state,
    const float* __restrict__ uW1, const float* __restrict__ ub1,
    const float* __restrict__ uW2, const float* __restrict__ ub2,
    const float* __restrict__ uW3, const float* __restrict__ ub3,
    const float* __restrict__ ab1, const float* __restrict__ ab2,
    const float* __restrict__ aW3, const float* __restrict__ ab3,
    const float* __restrict__ mb1, const float* __restrict__ mb2,
    const float* __restrict__ mb3,
    const u16* __restrict__ wsp, float* __restrict__ out) {
  __shared__ __align__(16) union { BU_F bu; TD_F td; } S;
  __shared__ u16 msgs[RPB_F][kL][64];
  __shared__ float mcur[RPB_F][64];
  const int tid = threadIdx.x;
  const int wv = tid >> 6, lane = tid & 63;
  const int r15 = lane & 15, g = lane >> 4;
  const int rA = 2 * wv, rB = 2 * wv + 1;
  const int rowBase = blockIdx.x * RPB_F;
  for (int i = tid; i < 64 * 64; i += NTHR_F) S.bu.sW1[i >> 6][i & 63] = uW1[i];
  for (int i = tid; i < 128 * 64; i += NTHR_F) S.bu.sW2[i >> 6][i & 63] = uW2[i];
  for (int i = tid; i < 64 * 64; i += NTHR_F) S.bu.sW3[i >> 6][i & 63] = uW3[i];
  for (int i = tid; i < RPB_F * 64; i += NTHR_F) (&mcur[0][0])[i] = 0.f;
  const float bu1 = ub1[lane], bu2 = ub2[lane], bu3 = ub3[lane];
  __syncthreads();
  for (int t = kL - 1; t >= 0; --t) {
    for (int i = tid; i < RPB_F * 64; i += NTHR_F) {
      const int r = i >> 6, s = i & 63;
      S.bu.bufS[r][s] = state[((size_t)(rowBase + r) * kL + t) * 64 + s];
    }
    __syncthreads();
    {
      float a0 = bu1, a1 = bu1;
      #pragma unroll 4
      for (int k = 0; k < 64; ++k) {
        const float w = S.bu.sW1[k][lane];
        a0 = fmaf(S.bu.bufS[rA][k], w, a0);
        a1 = fmaf(S.bu.bufS[rB][k], w, a1);
      }
      const float i0 = 1.f / fmaxf(sqrtf(wsum64(a0 * a0)), 1e-12f);
      const float i1 = 1.f / fmaxf(sqrtf(wsum64(a1 * a1)), 1e-12f);
      S.bu.bufX[rA][lane] = tanhf(a0 * i0);
      S.bu.bufX[rB][lane] = tanhf(a1 * i1);
      S.bu.bufX[rA][64 + lane] = tanhf(mcur[rA][lane]);
      S.bu.bufX[rB][64 + lane] = tanhf(mcur[rB][lane]);
    }
    {
      float a0 = bu2, a1 = bu2;
      #pragma unroll 4
      for (int k = 0; k < 128; ++k) {
        const float w = S.bu.sW2[k][lane];
        a0 = fmaf(S.bu.bufX[rA][k], w, a0);
        a1 = fmaf(S.bu.bufX[rB][k], w, a1);
      }
      S.bu.bufS[rA][lane] = tanhf(a0);
      S.bu.bufS[rB][lane] = tanhf(a1);
    }
    {
      float a0 = bu3, a1 = bu3;
      #pragma unroll 4
      for (int k = 0; k < 64; ++k) {
        const float w = S.bu.sW3[k][lane];
        a0 = fmaf(S.bu.bufS[rA][k], w, a0);
        a1 = fmaf(S.bu.bufS[rB][k], w, a1);
      }
      const float i0 = 1.f / fmaxf(sqrtf(wsum64(a0 * a0)), 1e-12f);
      const float i1 = 1.f / fmaxf(sqrtf(wsum64(a1 * a1)), 1e-12f);
      const float m0 = a0 * i0, m1 = a1 * i1;
      msgs[rA][t][lane] = f2bf(m0);
      msgs[rB][t][lane] = f2bf(m1);
      mcur[rA][lane] = m0;
      mcur[rB][lane] = m1;
    }
    __syncthreads();
  }
  for (int i = tid; i < RPB_F * 64; i += NTHR_F) (&mcur[0][0])[i] = 0.f;
  __syncthreads();
  const float ab3v = ab3[0];
  for (int t = 0; t < kL; ++t) {
    for (int i = tid; i < RPB_F * 128; i += NTHR_F) {
      const int r = i >> 7, c = i & 127;
      const float v = (c < 64) ? bf2f(msgs[r][t][c]) : mcur[r][c - 64];
      u16 h, l;
      split2(tanhf(v), h, l);
      S.td.xmH[r][c] = h;
      S.td.xmL[r][c] = l;
    }
    __syncthreads();
    mfma_layer_f<128, 256, true>(&S.td.xmH[0][0], &S.td.xmL[0][0], 136, wsp + OFF_A1, ab1,
                                 &S.td.bAH[0][0], &S.td.bAL[0][0], 264, wv, r15, g);
    __syncthreads();
    mfma_layer_f<256, 256, true>(&S.td.bAH[0][0], &S.td.bAL[0][0], 264, wsp + OFF_A2, ab2,
                                 &S.td.bBH[0][0], &S.td.bBL[0][0], 264, wv, r15, g);
    __syncthreads();
    {
      float p0 = 0.f, p1 = 0.f;
      #pragma unroll
      for (int j = 0; j < 4; ++j) {
        const int c = j * 64 + lane;
        const float w = aW3[c];
        p0 = fmaf(bf2f(S.td.bBH[rA][c]) + bf2f(S.td.bBL[rA][c]), w, p0);
        p1 = fmaf(bf2f(S.td.bBH[rB][c]) + bf2f(S.td.bBL[rB][c]), w, p1);
      }
      p0 = wsum64(p0);
      p1 = wsum64(p1);
      if (lane == 0) {
        out[(size_t)(rowBase + rA) * kL + t] = tanhf(p0 + ab3v);
        out[(size_t)(rowBase + rB) * kL + t] = tanhf(p1 + ab3v);
      }
    }
    mfma_layer_f<128, 256, true>(&S.td.xmH[0][0], &S.td.xmL[0][0], 136, wsp + OFF_M1, mb1,
                                 &S.td.bAH[0][0], &S.td.bAL[0][0], 264, wv, r15, g);
    __syncthreads();
    mfma_layer_f<256, 256, true>(&S.td.bAH[0][0], &S.td.bAL[0][0], 264, wsp + OFF_M2, mb2,
                                 &S.td.bBH[0][0], &S.td.bBL[0][0], 264, wv, r15, g);
    __syncthreads();
    {
      constexpr int K = 256, N = 64;
      const int nt0 = wv * 2;
      if (nt0 < 4) {
        const int c0 = nt0 * 16 + r15;
        f32x4 acc0 = {0.f, 0.f, 0.f, 0.f}, acc1 = acc0;
        #pragma unroll
        for (int kt = 0; kt < K / 32; ++kt) {
          const int abase = r15 * 264 + kt * 32 + g * 8;
          s16x8 ah = ldsf(&S.td.bBH[0][0] + abase), al = ldsf(&S.td.bBL[0][0] + abase);
          const u16* b0 = wsp + OFF_M3 + (size_t)((kt * N + c0) * 2) * 32 + g * 8;
          const u16* b1 = wsp + OFF_M3 + (size_t)((kt * N + c0 + 16) * 2) * 32 + g * 8;
          s16x8 b0h = ldsf(b0), b0l = ldsf(b0 + 32);
          s16x8 b1h = ldsf(b1), b1l = ldsf(b1 + 32);
          acc0 = mfma16(ah, b0h, acc0); acc0 = mfma16(al, b0h, acc0); acc0 = mfma16(ah, b0l, acc0);
          acc1 = mfma16(ah, b1h, acc1); acc1 = mfma16(al, b1h, acc1); acc1 = mfma16(ah, b1l, acc1);
        }
        #pragma unroll
        for (int nt = 0; nt < 2; ++nt) {
          const int col = c0 + nt * 16;
          const float bb = mb3[col];
          const f32x4 a = nt ? acc1 : acc0;
          #pragma unroll
          for (int i = 0; i < 4; ++i) S.td.md[g * 4 + i][col] = a[i] + bb;
        }
      }
    }
    __syncthreads();
    {
      const float v0 = S.td.md[rA][lane], v1 = S.td.md[rB][lane];
      const float i0 = 1.f / fmaxf(sqrtf(wsum64(v0 * v0)), 1e-12f);
      const float i1 = 1.f / fmaxf(sqrtf(wsum64(v1 * v1)), 1e-12f);
      mcur[rA][lane] = v0 * i0;
      mcur[rB][lane] = v1 * i1;
    }
    __syncthreads();
  }
}

extern "C" void kernel_launch(void* const* d_in, const int* in_sizes, int n_in,
                              void* d_out, int out_size, void* d_ws, size_t ws_size,
                              hipStream_t stream) {
  (void)in_sizes; (void)n_in; (void)out_size;
  const float* state = (const float*)d_in[0];
  const float* uW1 = (const float*)d_in[1];
  const float* ub1 = (const float*)d_in[2];
  const float* uW2 = (const float*)d_in[3];
  const float* ub2 = (const float*)d_in[4];
  const float* uW3 = (const float*)d_in[5];
  const float* ub3 = (const float*)d_in[6];
  const float* aW1 = (const float*)d_in[7];
  const float* ab1 = (const float*)d_in[8];
  const float* aW2 = (const float*)d_in[9];
  const float* ab2 = (const float*)d_in[10];
  const float* aW3 = (const float*)d_in[11];
  const float* ab3 = (const float*)d_in[12];
  const float* mW1 = (const float*)d_in[13];
  const float* mb1 = (const float*)d_in[14];
  const float* mW2 = (const float*)d_in[15];
  const float* mb2 = (const float*)d_in[16];
  const float* mW3 = (const float*)d_in[17];
  const float* mb3 = (const float*)d_in[18];
  u16* wsp = (u16*)d_ws;
  float* out = (float*)d_out;

  if (ws_size >= WS_NEED) {
    float* pt = reinterpret_cast<float*>(wsp + PT_OFF);
    hipLaunchKernelGGL(prep_kernel, dim3(896), dim3(256), 0, stream,
                       aW1, aW2, mW1, mW2, mW3, uW1, uW2, uW3, wsp, 9);
    hipLaunchKernelGGL(k1_kernel, dim3(kB * kL / 32), dim3(512), 0, stream,
                       state, ub1, ub2, wsp, pt);
    hipLaunchKernelGGL(k24_kernel, dim3(kB / 32), dim3(512), 0, stream,
                       ub3, ab1, ab2, aW3, ab3, mb1, mb2, mb3, wsp, pt, out);
  } else {
    hipLaunchKernelGGL(prep_kernel, dim3(896), dim3(256), 0, stream,
                       aW1, aW2, mW1, mW2, mW3, uW1, uW2, uW3, wsp, 5);
    hipLaunchKernelGGL(actor_fallback_kernel, dim3(kB / RPB_F), dim3(NTHR_F), 0, stream,
                       state, uW1, ub1, uW2, ub2, uW3, ub3,
                       ab1, ab2, aW3, ab3, mb1, mb2, mb3, wsp, out);
  }
}

// Round 4
// 3273.473 us; speedup vs baseline: 1.6167x; 1.6167x over previous
//
#include <hip/hip_runtime.h>

typedef unsigned int u32;
typedef unsigned long long u64;
typedef unsigned short u16;
typedef short s16x8 __attribute__((ext_vector_type(8)));
typedef float f32x4 __attribute__((ext_vector_type(4)));
typedef float f32x2 __attribute__((ext_vector_type(2)));

namespace {
constexpr int kB = 16384, kL = 20;

// packed split-bf16 weights in d_ws (u16 elems). per (kt,n): hi[32] | lo[32]
constexpr int OFF_A1 = 0;                       // 128x256
constexpr int OFF_A2 = OFF_A1 + 128 * 256 * 2;  // 256x256
constexpr int OFF_M1 = OFF_A2 + 256 * 256 * 2;  // 128x256
constexpr int OFF_M2 = OFF_M1 + 128 * 256 * 2;  // 256x256
constexpr int OFF_M3 = OFF_M2 + 256 * 256 * 2;  // 256x64
constexpr int OFF_U1 = OFF_M3 + 256 * 64 * 2;   // 64x64
constexpr int OFF_U2 = OFF_U1 + 64 * 64 * 2;    // 128x64
constexpr int OFF_U3 = OFF_U2 + 128 * 64 * 2;   // 64x64
constexpr int PACK_ELEMS = OFF_U3 + 64 * 64 * 2;          // 458752 u16
constexpr size_t XM_OFF = (size_t)PACK_ELEMS;             // u16 index
constexpr size_t WS_NEED = XM_OFF * 2 + (size_t)kB * kL * 128 * 2;  // 84,803,584 B

__device__ __forceinline__ u16 f2bf(float x) {
  u32 b = __builtin_bit_cast(u32, x);
  b += 0x7FFFu + ((b >> 16) & 1u);
  return (u16)(b >> 16);
}
__device__ __forceinline__ float bf2f(u16 h) {
  return __builtin_bit_cast(float, (u32)h << 16);
}
__device__ __forceinline__ void split2(float x, u16& hi, u16& lo) {
  hi = f2bf(x);
  lo = f2bf(x - bf2f(hi));
}
__device__ __forceinline__ f32x4 mfma16(s16x8 a, s16x8 b, f32x4 c) {
  return __builtin_amdgcn_mfma_f32_16x16x32_bf16(a, b, c, 0, 0, 0);
}
__device__ __forceinline__ s16x8 ldsf(const u16* p) {
  return *reinterpret_cast<const s16x8*>(p);
}
__device__ __forceinline__ float rsum32(float ss) {  // reduce over 32-lane half
  ss += __shfl_xor(ss, 16); ss += __shfl_xor(ss, 8);
  ss += __shfl_xor(ss, 4);  ss += __shfl_xor(ss, 2);
  ss += __shfl_xor(ss, 1);
  return ss;
}
__device__ __forceinline__ int swz(int row, int idx) { return idx ^ ((row & 7) << 3); }

// 3-term split-bf16 tile accumulate: A hi/lo planes in LDS, B packed in global
template <int K, int LD, int N, int NT>
__device__ __forceinline__ void mm3(const u16* __restrict__ AH, const u16* __restrict__ AL,
                                    const u16* __restrict__ Bp,
                                    int rowA, int c0, int g, f32x4 (&acc)[NT]) {
  #pragma unroll
  for (int kt = 0; kt < K / 32; ++kt) {
    const int off = swz(rowA, rowA * LD + kt * 32 + g * 8);
    s16x8 ah = ldsf(AH + off);
    s16x8 al = ldsf(AL + off);
    #pragma unroll
    for (int nt = 0; nt < NT; ++nt) {
      const u16* bp = Bp + (kt * N + c0 + nt * 16) * 64 + g * 8;
      s16x8 bh = *reinterpret_cast<const s16x8*>(bp);
      s16x8 bl = *reinterpret_cast<const s16x8*>(bp + 32);
      acc[nt] = mfma16(ah, bh, acc[nt]);
      acc[nt] = mfma16(al, bh, acc[nt]);
      acc[nt] = mfma16(ah, bl, acc[nt]);
    }
  }
}
}  // namespace

// ---------------- prep: pack weights into split-bf16 frag layout ----------------
__global__ __launch_bounds__(256) void prep_kernel(
    const float* __restrict__ aW1, const float* __restrict__ aW2,
    const float* __restrict__ mW1, const float* __restrict__ mW2,
    const float* __restrict__ mW3, const float* __restrict__ uW1,
    const float* __restrict__ uW2, const float* __restrict__ uW3,
    u16* __restrict__ ws) {
  const float* Ws[8] = {aW1, aW2, mW1, mW2, mW3, uW1, uW2, uW3};
  const int Ns[8]  = {256, 256, 256, 256, 64, 64, 64, 64};
  const int dst[8] = {OFF_A1, OFF_A2, OFF_M1, OFF_M2, OFF_M3, OFF_U1, OFF_U2, OFF_U3};
  const int cnt[8] = {32768, 65536, 32768, 65536, 16384, 4096, 8192, 4096};
  const int total = 229376;
  for (int e = blockIdx.x * 256 + threadIdx.x; e < total; e += gridDim.x * 256) {
    int l = 0, base = 0;
    while (e - base >= cnt[l]) { base += cnt[l]; ++l; }
    const int s = e - base, N = Ns[l];
    const int k = s / N, n = s % N;
    u16 hi, lo;
    split2(Ws[l][s], hi, lo);
    const int ob = dst[l] + ((k >> 5) * N + n) * 64 + (k & 31);
    ws[ob] = hi;
    ws[ob + 32] = lo;
  }
}

// ------------- rec: bottom-up + top-down M-path (RPB=16, 8 waves) -------------
__global__ __launch_bounds__(512, 4) void rec_kernel(
    const float* __restrict__ state,
    const float* __restrict__ ub1, const float* __restrict__ ub2,
    const float* __restrict__ ub3, const float* __restrict__ mb1,
    const float* __restrict__ mb2, const float* __restrict__ mb3,
    const u16* __restrict__ wsp, u16* __restrict__ xmh) {
  __shared__ __align__(16) u16 xmH[16 * 128], xmL[16 * 128];  // 4 KB each
  __shared__ __align__(16) u16 b1H[16 * 256], b1L[16 * 256];  // 8 KB each
  __shared__ __align__(16) u16 b2H[16 * 256], b2L[16 * 256];  // 8 KB each
  __shared__ __align__(16) u16 msgs[16 * kL * 64];            // 40 KB
  float* smc = reinterpret_cast<float*>(b1H + 2048);  // 16x64 f32, aliases b1H high
  u16* xsH = b1H; u16* xsL = b1L;                     // 16x64 planes (BU staging)
  u16* h2H = b2H; u16* h2L = b2L;                     // 16x64 planes (BU h2)

  const int tid = threadIdx.x;
  const int wv = tid >> 6, lane = tid & 63;
  const int r15 = lane & 15, g = lane >> 4;
  const int rowBase = blockIdx.x * 16;
  const int nr = tid >> 5, np = tid & 31;  // norm-phase: row / lane-in-row

  for (int i = tid; i < 2048; i += 512) { xmH[i] = 0; xmL[i] = 0; }
  __syncthreads();

  // ---- bottom-up: t = 19..0 ----
  for (int t = kL - 1; t >= 0; --t) {
    {  // s0: stage state -> xs planes
      const int idx = tid * 2, row = idx >> 6, c = idx & 63;
      f32x2 v = *reinterpret_cast<const f32x2*>(
          state + ((size_t)(rowBase + row) * kL + t) * 64 + c);
      u16 h0, l0, h1, l1;
      split2(v[0], h0, l0); split2(v[1], h1, l1);
      const int o = swz(row, row * 64 + c);
      *(u32*)&xsH[o] = (u32)h0 | ((u32)h1 << 16);
      *(u32*)&xsL[o] = (u32)l0 | ((u32)l1 << 16);
    }
    __syncthreads();
    if (wv < 4) {  // s1: u1
      f32x4 acc[1] = {{0.f, 0.f, 0.f, 0.f}};
      mm3<64, 64, 64, 1>(xsH, xsL, wsp + OFF_U1, r15, wv * 16 + r15, g, acc);
      const float bb = ub1[wv * 16 + r15];
      #pragma unroll
      for (int i = 0; i < 4; ++i) smc[(g * 4 + i) * 64 + wv * 16 + r15] = acc[0][i] + bb;
    }
    __syncthreads();
    {  // s2: normalize + tanh -> xm[0:64]
      const int c = np * 2;
      float v0 = smc[nr * 64 + c], v1 = smc[nr * 64 + c + 1];
      const float inv = 1.f / fmaxf(sqrtf(rsum32(v0 * v0 + v1 * v1)), 1e-12f);
      float t0 = tanhf(v0 * inv), t1 = tanhf(v1 * inv);
      u16 h0, l0, h1, l1;
      split2(t0, h0, l0); split2(t1, h1, l1);
      const int o = swz(nr, nr * 128 + c);
      *(u32*)&xmH[o] = (u32)h0 | ((u32)h1 << 16);
      *(u32*)&xmL[o] = (u32)l0 | ((u32)l1 << 16);
    }
    __syncthreads();
    if (wv < 4) {  // s3: u2 (K=128: [th | tanh(m)])
      f32x4 acc[1] = {{0.f, 0.f, 0.f, 0.f}};
      mm3<128, 128, 64, 1>(xmH, xmL, wsp + OFF_U2, r15, wv * 16 + r15, g, acc);
      const float bb = ub2[wv * 16 + r15];
      #pragma unroll
      for (int i = 0; i < 4; ++i) {
        const float hv = tanhf(acc[0][i] + bb);
        u16 h, l;
        split2(hv, h, l);
        const int row = g * 4 + i;
        const int o = swz(row, row * 64 + wv * 16 + r15);
        h2H[o] = h; h2L[o] = l;
      }
    }
    __syncthreads();
    if (wv < 4) {  // s4: u3
      f32x4 acc[1] = {{0.f, 0.f, 0.f, 0.f}};
      mm3<64, 64, 64, 1>(h2H, h2L, wsp + OFF_U3, r15, wv * 16 + r15, g, acc);
      const float bb = ub3[wv * 16 + r15];
      #pragma unroll
      for (int i = 0; i < 4; ++i) smc[(g * 4 + i) * 64 + wv * 16 + r15] = acc[0][i] + bb;
    }
    __syncthreads();
    {  // s5: normalize -> msg; msgs LDS; export msg bf16; tanh(msg) -> xm[64:]
      const int c = np * 2;
      float v0 = smc[nr * 64 + c], v1 = smc[nr * 64 + c + 1];
      const float inv = 1.f / fmaxf(sqrtf(rsum32(v0 * v0 + v1 * v1)), 1e-12f);
      const float m0 = v0 * inv, m1 = v1 * inv;
      const u32 mw = (u32)f2bf(m0) | ((u32)f2bf(m1) << 16);
      *(u32*)&msgs[nr * (kL * 64) + t * 64 + c] = mw;
      __builtin_nontemporal_store(
          mw, (u32*)(xmh + ((size_t)(rowBase + nr) * kL + t) * 128 + c));
      float q0 = tanhf(m0), q1 = tanhf(m1);
      u16 h0, l0, h1, l1;
      split2(q0, h0, l0); split2(q1, h1, l1);
      const int o = swz(nr, nr * 128 + 64 + c);
      *(u32*)&xmH[o] = (u32)h0 | ((u32)h1 << 16);
      *(u32*)&xmL[o] = (u32)l0 | ((u32)l1 << 16);
    }
    __syncthreads();
  }

  // reset m-state to 0 for top-down
  for (int i = tid; i < 1024; i += 512) {
    const int row = i >> 6, c = i & 63;
    const int o = swz(row, row * 128 + 64 + c);
    xmH[o] = 0; xmL[o] = 0;
  }
  __syncthreads();

  // ---- top-down: t = 0..19 (M-path only) ----
  for (int t = 0; t < kL; ++t) {
    {  // p0: xm[0:64] = tanh(msg)
      const int idx = tid * 2, row = idx >> 6, c = idx & 63;
      const u32 mw = *(const u32*)&msgs[row * (kL * 64) + t * 64 + c];
      float v0 = tanhf(bf2f((u16)mw)), v1 = tanhf(bf2f((u16)(mw >> 16)));
      u16 h0, l0, h1, l1;
      split2(v0, h0, l0); split2(v1, h1, l1);
      const int o = swz(row, row * 128 + c);
      *(u32*)&xmH[o] = (u32)h0 | ((u32)h1 << 16);
      *(u32*)&xmL[o] = (u32)l0 | ((u32)l1 << 16);
    }
    __syncthreads();
    {  // p1: M1 -> b1 (K=128, N=256, NT=2)
      f32x4 acc[2] = {};
      mm3<128, 128, 256, 2>(xmH, xmL, wsp + OFF_M1, r15, wv * 32 + r15, g, acc);
      #pragma unroll
      for (int nt = 0; nt < 2; ++nt) {
        const int col = wv * 32 + nt * 16 + r15;
        const float bb = mb1[col];
        #pragma unroll
        for (int i = 0; i < 4; ++i) {
          const float vv = fmaxf(acc[nt][i] + bb, 0.f);
          u16 h, l;
          split2(vv, h, l);
          const int row = g * 4 + i;
          const int o = swz(row, row * 256 + col);
          b1H[o] = h; b1L[o] = l;
        }
      }
    }
    __syncthreads();
    {  // p2: M2 -> b2 (K=256, N=256, NT=2)
      f32x4 acc[2] = {};
      mm3<256, 256, 256, 2>(b1H, b1L, wsp + OFF_M2, r15, wv * 32 + r15, g, acc);
      #pragma unroll
      for (int nt = 0; nt < 2; ++nt) {
        const int col = wv * 32 + nt * 16 + r15;
        const float bb = mb2[col];
        #pragma unroll
        for (int i = 0; i < 4; ++i) {
          const float vv = fmaxf(acc[nt][i] + bb, 0.f);
          u16 h, l;
          split2(vv, h, l);
          const int row = g * 4 + i;
          const int o = swz(row, row * 256 + col);
          b2H[o] = h; b2L[o] = l;
        }
      }
    }
    __syncthreads();
    if (wv < 4) {  // p3a: M3 -> smc (b1 dead now; smc aliases b1H high)
      f32x4 acc[1] = {{0.f, 0.f, 0.f, 0.f}};
      mm3<256, 256, 64, 1>(b2H, b2L, wsp + OFF_M3, r15, wv * 16 + r15, g, acc);
      const float bb = mb3[wv * 16 + r15];
      #pragma unroll
      for (int i = 0; i < 4; ++i) smc[(g * 4 + i) * 64 + wv * 16 + r15] = acc[0][i] + bb;
    } else {  // p3b: export tanh(m_t) hi (current xm[64:])
      const int base = (tid - 256) * 4;
      const int row = base >> 6, c = base & 63;
      u16 e0 = xmH[swz(row, row * 128 + 64 + c)];
      u16 e1 = xmH[swz(row, row * 128 + 64 + c + 1)];
      u16 e2 = xmH[swz(row, row * 128 + 64 + c + 2)];
      u16 e3 = xmH[swz(row, row * 128 + 64 + c + 3)];
      const u64 w = (u64)e0 | ((u64)e1 << 16) | ((u64)e2 << 32) | ((u64)e3 << 48);
      __builtin_nontemporal_store(
          w, (u64*)(xmh + ((size_t)(rowBase + row) * kL + t) * 128 + 64 + c));
    }
    __syncthreads();
    {  // p4: normalize -> m; tanh(m) split -> xm[64:]
      const int c = np * 2;
      float v0 = smc[nr * 64 + c], v1 = smc[nr * 64 + c + 1];
      const float inv = 1.f / fmaxf(sqrtf(rsum32(v0 * v0 + v1 * v1)), 1e-12f);
      float q0 = tanhf(v0 * inv), q1 = tanhf(v1 * inv);
      u16 h0, l0, h1, l1;
      split2(q0, h0, l0); split2(q1, h1, l1);
      const int o = swz(nr, nr * 128 + 64 + c);
      *(u32*)&xmH[o] = (u32)h0 | ((u32)h1 << 16);
      *(u32*)&xmL[o] = (u32)l0 | ((u32)l1 << 16);
    }
    __syncthreads();
  }
}

// ------------- head: batched action MLP over all (b,t) (32 items/block) -------------
__global__ __launch_bounds__(512, 4) void head_kernel(
    const float* __restrict__ ab1, const float* __restrict__ ab2,
    const float* __restrict__ aW3, const float* __restrict__ ab3,
    const u16* __restrict__ wsp, const u16* __restrict__ xmh,
    float* __restrict__ out) {
  __shared__ __align__(16) u16 xmHs[32 * 128], xmLs[32 * 128];  // 8 KB each
  __shared__ __align__(16) u16 h1H[32 * 256], h1L[32 * 256];    // 16 KB each
  __shared__ __align__(16) u16 h2H[32 * 256], h2L[32 * 256];    // 16 KB each
  const int tid = threadIdx.x;
  const int wv = tid >> 6, lane = tid & 63;
  const int r15 = lane & 15, g = lane >> 4;
  const int mh = wv >> 2, nq = wv & 3;
  const int rowA = mh * 16 + r15;
  const size_t i0 = (size_t)blockIdx.x * 32;

  {  // stage xm: cols 0-63 = raw msg bf16 -> tanh + full split; cols 64-127 = hi-only
    const int idx = tid * 8, row = idx >> 7, c = idx & 127;
    s16x8 v = __builtin_nontemporal_load(
        reinterpret_cast<const s16x8*>(xmh + (i0 + row) * 128 + c));
    s16x8 hh, ll;
    if (c < 64) {
      #pragma unroll
      for (int j = 0; j < 8; ++j) {
        u16 h, l;
        split2(tanhf(bf2f((u16)v[j])), h, l);
        hh[j] = (short)h; ll[j] = (short)l;
      }
    } else {
      hh = v;
      #pragma unroll
      for (int j = 0; j < 8; ++j) ll[j] = 0;
    }
    const int o = swz(row, row * 128 + c);
    *reinterpret_cast<s16x8*>(&xmHs[o]) = hh;
    *reinterpret_cast<s16x8*>(&xmLs[o]) = ll;
  }
  __syncthreads();
  {  // A1 -> h1
    f32x4 acc[4] = {};
    mm3<128, 128, 256, 4>(xmHs, xmLs, wsp + OFF_A1, rowA, nq * 64 + r15, g, acc);
    #pragma unroll
    for (int nt = 0; nt < 4; ++nt) {
      const int col = nq * 64 + nt * 16 + r15;
      const float bb = ab1[col];
      #pragma unroll
      for (int i = 0; i < 4; ++i) {
        const float vv = fmaxf(acc[nt][i] + bb, 0.f);
        u16 h, l;
        split2(vv, h, l);
        const int row = mh * 16 + g * 4 + i;
        const int o = swz(row, row * 256 + col);
        h1H[o] = h; h1L[o] = l;
      }
    }
  }
  __syncthreads();
  {  // A2 -> h2
    f32x4 acc[4] = {};
    mm3<256, 256, 256, 4>(h1H, h1L, wsp + OFF_A2, rowA, nq * 64 + r15, g, acc);
    #pragma unroll
    for (int nt = 0; nt < 4; ++nt) {
      const int col = nq * 64 + nt * 16 + r15;
      const float bb = ab2[col];
      #pragma unroll
      for (int i = 0; i < 4; ++i) {
        const float vv = fmaxf(acc[nt][i] + bb, 0.f);
        u16 h, l;
        split2(vv, h, l);
        const int row = mh * 16 + g * 4 + i;
        const int o = swz(row, row * 256 + col);
        h2H[o] = h; h2L[o] = l;
      }
    }
  }
  __syncthreads();
  {  // A3: dot(h2, aW3) + tanh -> out
    const int r = tid >> 4, p = tid & 15;
    const int o0 = swz(r, r * 256 + p * 16);
    const int o1 = swz(r, r * 256 + p * 16 + 8);
    s16x8 a0 = ldsf(h2H + o0), a1 = ldsf(h2H + o1);
    s16x8 b0 = ldsf(h2L + o0), b1 = ldsf(h2L + o1);
    float sum = 0.f;
    #pragma unroll
    for (int j = 0; j < 8; ++j) {
      sum += (bf2f((u16)a0[j]) + bf2f((u16)b0[j])) * aW3[p * 16 + j];
      sum += (bf2f((u16)a1[j]) + bf2f((u16)b1[j])) * aW3[p * 16 + 8 + j];
    }
    sum += __shfl_xor(sum, 8); sum += __shfl_xor(sum, 4);
    sum += __shfl_xor(sum, 2); sum += __shfl_xor(sum, 1);
    if (p == 0) out[i0 + r] = tanhf(sum + ab3[0]);
  }
}

extern "C" void kernel_launch(void* const* d_in, const int* in_sizes, int n_in,
                              void* d_out, int out_size, void* d_ws, size_t ws_size,
                              hipStream_t stream) {
  (void)in_sizes; (void)n_in; (void)out_size;
  const float* state = (const float*)d_in[0];
  const float* uW1 = (const float*)d_in[1];
  const float* ub1 = (const float*)d_in[2];
  const float* uW2 = (const float*)d_in[3];
  const float* ub2 = (const float*)d_in[4];
  const float* uW3 = (const float*)d_in[5];
  const float* ub3 = (const float*)d_in[6];
  const float* aW1 = (const float*)d_in[7];
  const float* ab1 = (const float*)d_in[8];
  const float* aW2 = (const float*)d_in[9];
  const float* ab2 = (const float*)d_in[10];
  const float* aW3 = (const float*)d_in[11];
  const float* ab3 = (const float*)d_in[12];
  const float* mW1 = (const float*)d_in[13];
  const float* mb1 = (const float*)d_in[14];
  const float* mW2 = (const float*)d_in[15];
  const float* mb2 = (const float*)d_in[16];
  const float* mW3 = (const float*)d_in[17];
  const float* mb3 = (const float*)d_in[18];
  u16* wsp = (u16*)d_ws;
  float* out = (float*)d_out;

  if (ws_size < WS_NEED) return;  // empirically ws >= 84.8 MB (r3 ran this size)
  u16* xmh = wsp + XM_OFF;

  hipLaunchKernelGGL(prep_kernel, dim3(896), dim3(256), 0, stream,
                     aW1, aW2, mW1, mW2, mW3, uW1, uW2, uW3, wsp);
  hipLaunchKernelGGL(rec_kernel, dim3(kB / 16), dim3(512), 0, stream,
                     state, ub1, ub2, ub3, mb1, mb2, mb3, wsp, xmh);
  hipLaunchKernelGGL(head_kernel, dim3(kB * kL / 32), dim3(512), 0, stream,
                     ab1, ab2, aW3, ab3, wsp, xmh, out);
}

// Round 5
// 1555.282 us; speedup vs baseline: 3.4026x; 2.1047x over previous
//
#include <hip/hip_runtime.h>

typedef unsigned int u32;
typedef unsigned short u16;
typedef short s16x8 __attribute__((ext_vector_type(8)));
typedef float f32x4 __attribute__((ext_vector_type(4)));

namespace {
constexpr int kB = 16384, kL = 20;
constexpr int RPB = 32;   // rows per block

// packed split-bf16 weights in d_ws (u16 elems). per (kt,n): hi[32] | lo[32]
constexpr int OFF_A1 = 0;                       // 128x256
constexpr int OFF_A2 = OFF_A1 + 128 * 256 * 2;  // 256x256
constexpr int OFF_M1 = OFF_A2 + 256 * 256 * 2;  // 128x256
constexpr int OFF_M2 = OFF_M1 + 128 * 256 * 2;  // 256x256
constexpr int OFF_M3 = OFF_M2 + 256 * 256 * 2;  // 256x64
constexpr int OFF_U1 = OFF_M3 + 256 * 64 * 2;   // 64x64
constexpr int OFF_U2 = OFF_U1 + 64 * 64 * 2;    // 128x64
constexpr int OFF_U3 = OFF_U2 + 128 * 64 * 2;   // 64x64
constexpr int PACK_ELEMS = OFF_U3 + 64 * 64 * 2;  // 458752 u16 = 896 KB
constexpr size_t WS_NEED = (size_t)PACK_ELEMS * 2;

__device__ __forceinline__ u16 f2bf(float x) {
  u32 b = __builtin_bit_cast(u32, x);
  b += 0x7FFFu + ((b >> 16) & 1u);
  return (u16)(b >> 16);
}
__device__ __forceinline__ float bf2f(u16 h) {
  return __builtin_bit_cast(float, (u32)h << 16);
}
__device__ __forceinline__ void split2(float x, u16& hi, u16& lo) {
  hi = f2bf(x);
  lo = f2bf(x - bf2f(hi));
}
__device__ __forceinline__ f32x4 mfma16(s16x8 a, s16x8 b, f32x4 c) {
  return __builtin_amdgcn_mfma_f32_16x16x32_bf16(a, b, c, 0, 0, 0);
}
__device__ __forceinline__ s16x8 ldsf(const u16* p) {
  return *reinterpret_cast<const s16x8*>(p);
}
__device__ __forceinline__ int swz(int row, int idx) { return idx ^ ((row & 7) << 3); }

// split-bf16 tile accumulate with B-reuse across NM m-tiles.
// A planes (hi/lo) in LDS (XOR-swizzled), B packed in global (L2-resident).
template <int K, int LD, int N, int NT, int NM>
__device__ __forceinline__ void mm3m(const u16* __restrict__ AH, const u16* __restrict__ AL,
                                     const u16* __restrict__ Bp,
                                     int mbase, int c0, int r15, int g,
                                     f32x4 (&acc)[NM][NT]) {
  #pragma unroll
  for (int kt = 0; kt < K / 32; ++kt) {
    s16x8 bh[NT], bl[NT];
    #pragma unroll
    for (int nt = 0; nt < NT; ++nt) {
      const u16* bp = Bp + (size_t)(kt * N + c0 + nt * 16) * 64 + g * 8;
      bh[nt] = *reinterpret_cast<const s16x8*>(bp);
      bl[nt] = *reinterpret_cast<const s16x8*>(bp + 32);
    }
    #pragma unroll
    for (int m = 0; m < NM; ++m) {
      const int row = mbase + m * 16 + r15;
      const int off = swz(row, row * LD + kt * 32 + g * 8);
      s16x8 ah = ldsf(AH + off);
      s16x8 al = ldsf(AL + off);
      #pragma unroll
      for (int nt = 0; nt < NT; ++nt) {
        acc[m][nt] = mfma16(ah, bh[nt], acc[m][nt]);
        acc[m][nt] = mfma16(al, bh[nt], acc[m][nt]);
        acc[m][nt] = mfma16(ah, bl[nt], acc[m][nt]);
      }
    }
  }
}
}  // namespace

// ---------------- prep: pack weights into split-bf16 frag layout ----------------
__global__ __launch_bounds__(256) void prep_kernel(
    const float* __restrict__ aW1, const float* __restrict__ aW2,
    const float* __restrict__ mW1, const float* __restrict__ mW2,
    const float* __restrict__ mW3, const float* __restrict__ uW1,
    const float* __restrict__ uW2, const float* __restrict__ uW3,
    u16* __restrict__ ws) {
  const float* Ws[8] = {aW1, aW2, mW1, mW2, mW3, uW1, uW2, uW3};
  const int Ns[8]  = {256, 256, 256, 256, 64, 64, 64, 64};
  const int dst[8] = {OFF_A1, OFF_A2, OFF_M1, OFF_M2, OFF_M3, OFF_U1, OFF_U2, OFF_U3};
  const int cnt[8] = {32768, 65536, 32768, 65536, 16384, 4096, 8192, 4096};
  const int total = 229376;
  for (int e = blockIdx.x * 256 + threadIdx.x; e < total; e += gridDim.x * 256) {
    int l = 0, base = 0;
    while (e - base >= cnt[l]) { base += cnt[l]; ++l; }
    const int s = e - base, N = Ns[l];
    const int k = s / N, n = s % N;
    u16 hi, lo;
    split2(Ws[l][s], hi, lo);
    const int ob = dst[l] + ((k >> 5) * N + n) * 64 + (k & 31);
    ws[ob] = hi;
    ws[ob + 32] = lo;
  }
}

// ------- monolith: BU + TD (incl. action head), RPB=32, zero side-streams -------
__global__ __launch_bounds__(512, 2) void actor_kernel(
    const float* __restrict__ state,
    const float* __restrict__ ub1, const float* __restrict__ ub2,
    const float* __restrict__ ub3,
    const float* __restrict__ ab1, const float* __restrict__ ab2,
    const float* __restrict__ aW3, const float* __restrict__ ab3,
    const float* __restrict__ mb1, const float* __restrict__ mb2,
    const float* __restrict__ mb3,
    const u16* __restrict__ wsp, float* __restrict__ out) {
  // 160 KB LDS, carved manually (u16 units):
  __shared__ __align__(16) u16 lds[81920];
  u16* XMH = lds;             // 32x128  [0, 4096)
  u16* XML = lds + 4096;      //         [4096, 8192)
  u16* B1H = lds + 8192;      // 32x256  [8192, 16384)
  u16* B1L = lds + 16384;     //         [16384, 24576)
  u16* B2H = lds + 24576;     // 32x256  [24576, 32768)
  u16* B2L = lds + 32768;     //         [32768, 40960)
  u16* MSGS = lds + 40960;    // 32x20x64 [40960, 81920)
  // BU-phase aliases (regions free at those times):
  u16* XSH = B1H;             // 32x64 state planes
  u16* XSL = B1H + 2048;
  float* SMC = reinterpret_cast<float*>(B1L);  // 32x64 f32 (8 KB)
  u16* H2H = B2H;             // 32x64
  u16* H2L = B2H + 2048;

  const int tid = threadIdx.x;
  const int wv = tid >> 6, lane = tid & 63;
  const int r15 = lane & 15, g = lane >> 4;
  const int mh = wv >> 2, nq = wv & 3;   // 64-col layer mapping (2m x 4n)
  const int nr = tid >> 4, np = tid & 15;  // norm mapping: 32 rows x 16 lanes
  const int rowBase = blockIdx.x * RPB;

  // zero m-state planes (xm cols 64..127)
  for (int i = tid; i < 2048; i += 512) {
    const int row = i >> 6, c = i & 63;
    const int o = swz(row, row * 128 + 64 + c);
    XMH[o] = 0; XML[o] = 0;
  }
  __syncthreads();

  // ---------------- bottom-up: t = 19..0 ----------------
  f32x4 vst = *reinterpret_cast<const f32x4*>(
      state + ((size_t)(rowBase + nr) * kL + (kL - 1)) * 64 + np * 4);
  for (int t = kL - 1; t >= 0; --t) {
    {  // s0: split state into XS planes; prefetch next t
      u16 h[4], l[4];
      #pragma unroll
      for (int j = 0; j < 4; ++j) split2(vst[j], h[j], l[j]);
      const int o = swz(nr, nr * 64 + np * 4);
      *(u32*)&XSH[o] = (u32)h[0] | ((u32)h[1] << 16);
      *(u32*)&XSH[o + 2] = (u32)h[2] | ((u32)h[3] << 16);
      *(u32*)&XSL[o] = (u32)l[0] | ((u32)l[1] << 16);
      *(u32*)&XSL[o + 2] = (u32)l[2] | ((u32)l[3] << 16);
      if (t > 0)
        vst = *reinterpret_cast<const f32x4*>(
            state + ((size_t)(rowBase + nr) * kL + (t - 1)) * 64 + np * 4);
    }
    __syncthreads();
    {  // s1: U1 -> SMC raw
      f32x4 acc[1][1] = {};
      mm3m<64, 64, 64, 1, 1>(XSH, XSL, wsp + OFF_U1, mh * 16, nq * 16 + r15, r15, g, acc);
      const float bb = ub1[nq * 16 + r15];
      #pragma unroll
      for (int i = 0; i < 4; ++i)
        SMC[(mh * 16 + g * 4 + i) * 64 + nq * 16 + r15] = acc[0][0][i] + bb;
    }
    __syncthreads();
    {  // s2: normalize + tanh -> xm[0:64]
      f32x4 v = *reinterpret_cast<const f32x4*>(SMC + nr * 64 + np * 4);
      float ss = v[0]*v[0] + v[1]*v[1] + v[2]*v[2] + v[3]*v[3];
      ss += __shfl_xor(ss, 8); ss += __shfl_xor(ss, 4);
      ss += __shfl_xor(ss, 2); ss += __shfl_xor(ss, 1);
      const float inv = 1.f / fmaxf(sqrtf(ss), 1e-12f);
      u16 h[4], l[4];
      #pragma unroll
      for (int j = 0; j < 4; ++j) split2(tanhf(v[j] * inv), h[j], l[j]);
      const int o = swz(nr, nr * 128 + np * 4);
      *(u32*)&XMH[o] = (u32)h[0] | ((u32)h[1] << 16);
      *(u32*)&XMH[o + 2] = (u32)h[2] | ((u32)h[3] << 16);
      *(u32*)&XML[o] = (u32)l[0] | ((u32)l[1] << 16);
      *(u32*)&XML[o + 2] = (u32)l[2] | ((u32)l[3] << 16);
    }
    __syncthreads();
    {  // s3: U2 (K=128) -> tanh -> H2 planes
      f32x4 acc[1][1] = {};
      mm3m<128, 128, 64, 1, 1>(XMH, XML, wsp + OFF_U2, mh * 16, nq * 16 + r15, r15, g, acc);
      const float bb = ub2[nq * 16 + r15];
      #pragma unroll
      for (int i = 0; i < 4; ++i) {
        u16 h, l;
        split2(tanhf(acc[0][0][i] + bb), h, l);
        const int row = mh * 16 + g * 4 + i;
        const int o = swz(row, row * 64 + nq * 16 + r15);
        H2H[o] = h; H2L[o] = l;
      }
    }
    __syncthreads();
    {  // s4: U3 -> SMC raw
      f32x4 acc[1][1] = {};
      mm3m<64, 64, 64, 1, 1>(H2H, H2L, wsp + OFF_U3, mh * 16, nq * 16 + r15, r15, g, acc);
      const float bb = ub3[nq * 16 + r15];
      #pragma unroll
      for (int i = 0; i < 4; ++i)
        SMC[(mh * 16 + g * 4 + i) * 64 + nq * 16 + r15] = acc[0][0][i] + bb;
    }
    __syncthreads();
    {  // s5: normalize -> msg (bf16 MSGS) ; xm[64:] = tanh(msg)
      f32x4 v = *reinterpret_cast<const f32x4*>(SMC + nr * 64 + np * 4);
      float ss = v[0]*v[0] + v[1]*v[1] + v[2]*v[2] + v[3]*v[3];
      ss += __shfl_xor(ss, 8); ss += __shfl_xor(ss, 4);
      ss += __shfl_xor(ss, 2); ss += __shfl_xor(ss, 1);
      const float inv = 1.f / fmaxf(sqrtf(ss), 1e-12f);
      float m[4];
      #pragma unroll
      for (int j = 0; j < 4; ++j) m[j] = v[j] * inv;
      const int mi = nr * (kL * 64) + t * 64 + np * 4;
      *(u32*)&MSGS[mi] = (u32)f2bf(m[0]) | ((u32)f2bf(m[1]) << 16);
      *(u32*)&MSGS[mi + 2] = (u32)f2bf(m[2]) | ((u32)f2bf(m[3]) << 16);
      u16 h[4], l[4];
      #pragma unroll
      for (int j = 0; j < 4; ++j) split2(tanhf(m[j]), h[j], l[j]);
      const int o = swz(nr, nr * 128 + 64 + np * 4);
      *(u32*)&XMH[o] = (u32)h[0] | ((u32)h[1] << 16);
      *(u32*)&XMH[o + 2] = (u32)h[2] | ((u32)h[3] << 16);
      *(u32*)&XML[o] = (u32)l[0] | ((u32)l[1] << 16);
      *(u32*)&XML[o + 2] = (u32)l[2] | ((u32)l[3] << 16);
    }
    __syncthreads();
  }

  // reset m-state to 0 for top-down
  for (int i = tid; i < 2048; i += 512) {
    const int row = i >> 6, c = i & 63;
    const int o = swz(row, row * 128 + 64 + c);
    XMH[o] = 0; XML[o] = 0;
  }
  __syncthreads();

  // ---------------- top-down: t = 0..19 ----------------
  const float ab3v = ab3[0];
  const int c0 = wv * 32 + r15;  // 256-col layer: wave owns 32 cols, loops 2 m-tiles
  for (int t = 0; t < kL; ++t) {
    {  // p0: xm[0:64] = split(tanh(msgs[t]))
      const int mi = nr * (kL * 64) + t * 64 + np * 4;
      const u32 w0 = *(const u32*)&MSGS[mi];
      const u32 w1 = *(const u32*)&MSGS[mi + 2];
      float v[4] = {bf2f((u16)w0), bf2f((u16)(w0 >> 16)),
                    bf2f((u16)w1), bf2f((u16)(w1 >> 16))};
      u16 h[4], l[4];
      #pragma unroll
      for (int j = 0; j < 4; ++j) split2(tanhf(v[j]), h[j], l[j]);
      const int o = swz(nr, nr * 128 + np * 4);
      *(u32*)&XMH[o] = (u32)h[0] | ((u32)h[1] << 16);
      *(u32*)&XMH[o + 2] = (u32)h[2] | ((u32)h[3] << 16);
      *(u32*)&XML[o] = (u32)l[0] | ((u32)l[1] << 16);
      *(u32*)&XML[o + 2] = (u32)l[2] | ((u32)l[3] << 16);
    }
    __syncthreads();
    {  // p1: A1 -> B1 (relu)
      f32x4 acc[2][2] = {};
      mm3m<128, 128, 256, 2, 2>(XMH, XML, wsp + OFF_A1, 0, c0, r15, g, acc);
      #pragma unroll
      for (int nt = 0; nt < 2; ++nt) {
        const int col = c0 + nt * 16;
        const float bb = ab1[col];
        #pragma unroll
        for (int m = 0; m < 2; ++m)
          #pragma unroll
          for (int i = 0; i < 4; ++i) {
            const int row = m * 16 + g * 4 + i;
            u16 h, l;
            split2(fmaxf(acc[m][nt][i] + bb, 0.f), h, l);
            const int o = swz(row, row * 256 + col);
            B1H[o] = h; B1L[o] = l;
          }
      }
    }
    __syncthreads();
    {  // p2: A2 -> B2 (relu)
      f32x4 acc[2][2] = {};
      mm3m<256, 256, 256, 2, 2>(B1H, B1L, wsp + OFF_A2, 0, c0, r15, g, acc);
      #pragma unroll
      for (int nt = 0; nt < 2; ++nt) {
        const int col = c0 + nt * 16;
        const float bb = ab2[col];
        #pragma unroll
        for (int m = 0; m < 2; ++m)
          #pragma unroll
          for (int i = 0; i < 4; ++i) {
            const int row = m * 16 + g * 4 + i;
            u16 h, l;
            split2(fmaxf(acc[m][nt][i] + bb, 0.f), h, l);
            const int o = swz(row, row * 256 + col);
            B2H[o] = h; B2L[o] = l;
          }
      }
    }
    __syncthreads();
    {  // p3: A3 (dot over B2 -> out) + M1 (xm -> B1, relu)
      const int o0 = swz(nr, nr * 256 + np * 16);
      const int o1 = swz(nr, nr * 256 + np * 16 + 8);
      s16x8 h0 = ldsf(B2H + o0), h1 = ldsf(B2H + o1);
      s16x8 l0 = ldsf(B2L + o0), l1 = ldsf(B2L + o1);
      float sum = 0.f;
      #pragma unroll
      for (int j = 0; j < 8; ++j) {
        sum += (bf2f((u16)h0[j]) + bf2f((u16)l0[j])) * aW3[np * 16 + j];
        sum += (bf2f((u16)h1[j]) + bf2f((u16)l1[j])) * aW3[np * 16 + 8 + j];
      }
      sum += __shfl_xor(sum, 8); sum += __shfl_xor(sum, 4);
      sum += __shfl_xor(sum, 2); sum += __shfl_xor(sum, 1);
      if (np == 0) out[(size_t)(rowBase + nr) * kL + t] = tanhf(sum + ab3v);

      f32x4 acc[2][2] = {};
      mm3m<128, 128, 256, 2, 2>(XMH, XML, wsp + OFF_M1, 0, c0, r15, g, acc);
      #pragma unroll
      for (int nt = 0; nt < 2; ++nt) {
        const int col = c0 + nt * 16;
        const float bb = mb1[col];
        #pragma unroll
        for (int m = 0; m < 2; ++m)
          #pragma unroll
          for (int i = 0; i < 4; ++i) {
            const int row = m * 16 + g * 4 + i;
            u16 h, l;
            split2(fmaxf(acc[m][nt][i] + bb, 0.f), h, l);
            const int o = swz(row, row * 256 + col);
            B1H[o] = h; B1L[o] = l;
          }
      }
    }
    __syncthreads();
    {  // p4: M2 -> B2 (relu)
      f32x4 acc[2][2] = {};
      mm3m<256, 256, 256, 2, 2>(B1H, B1L, wsp + OFF_M2, 0, c0, r15, g, acc);
      #pragma unroll
      for (int nt = 0; nt < 2; ++nt) {
        const int col = c0 + nt * 16;
        const float bb = mb2[col];
        #pragma unroll
        for (int m = 0; m < 2; ++m)
          #pragma unroll
          for (int i = 0; i < 4; ++i) {
            const int row = m * 16 + g * 4 + i;
            u16 h, l;
            split2(fmaxf(acc[m][nt][i] + bb, 0.f), h, l);
            const int o = swz(row, row * 256 + col);
            B2H[o] = h; B2L[o] = l;
          }
      }
    }
    __syncthreads();
    {  // p5: M3 -> SMC raw (B1 dead; SMC aliases B1L)
      f32x4 acc[1][1] = {};
      mm3m<256, 256, 64, 1, 1>(B2H, B2L, wsp + OFF_M3, mh * 16, nq * 16 + r15, r15, g, acc);
      const float bb = mb3[nq * 16 + r15];
      #pragma unroll
      for (int i = 0; i < 4; ++i)
        SMC[(mh * 16 + g * 4 + i) * 64 + nq * 16 + r15] = acc[0][0][i] + bb;
    }
    __syncthreads();
    {  // p6: normalize -> m ; xm[64:] = split(tanh(m))
      f32x4 v = *reinterpret_cast<const f32x4*>(SMC + nr * 64 + np * 4);
      float ss = v[0]*v[0] + v[1]*v[1] + v[2]*v[2] + v[3]*v[3];
      ss += __shfl_xor(ss, 8); ss += __shfl_xor(ss, 4);
      ss += __shfl_xor(ss, 2); ss += __shfl_xor(ss, 1);
      const float inv = 1.f / fmaxf(sqrtf(ss), 1e-12f);
      u16 h[4], l[4];
      #pragma unroll
      for (int j = 0; j < 4; ++j) split2(tanhf(v[j] * inv), h[j], l[j]);
      const int o = swz(nr, nr * 128 + 64 + np * 4);
      *(u32*)&XMH[o] = (u32)h[0] | ((u32)h[1] << 16);
      *(u32*)&XMH[o + 2] = (u32)h[2] | ((u32)h[3] << 16);
      *(u32*)&XML[o] = (u32)l[0] | ((u32)l[1] << 16);
      *(u32*)&XML[o + 2] = (u32)l[2] | ((u32)l[3] << 16);
    }
    __syncthreads();
  }
}

extern "C" void kernel_launch(void* const* d_in, const int* in_sizes, int n_in,
                              void* d_out, int out_size, void* d_ws, size_t ws_size,
                              hipStream_t stream) {
  (void)in_sizes; (void)n_in; (void)out_size;
  const float* state = (const float*)d_in[0];
  const float* uW1 = (const float*)d_in[1];
  const float* ub1 = (const float*)d_in[2];
  const float* uW2 = (const float*)d_in[3];
  const float* ub2 = (const float*)d_in[4];
  const float* uW3 = (const float*)d_in[5];
  const float* ub3 = (const float*)d_in[6];
  const float* aW1 = (const float*)d_in[7];
  const float* ab1 = (const float*)d_in[8];
  const float* aW2 = (const float*)d_in[9];
  const float* ab2 = (const float*)d_in[10];
  const float* aW3 = (const float*)d_in[11];
  const float* ab3 = (const float*)d_in[12];
  const float* mW1 = (const float*)d_in[13];
  const float* mb1 = (const float*)d_in[14];
  const float* mW2 = (const float*)d_in[15];
  const float* mb2 = (const float*)d_in[16];
  const float* mW3 = (const float*)d_in[17];
  const float* mb3 = (const float*)d_in[18];
  u16* wsp = (u16*)d_ws;
  float* out = (float*)d_out;

  if (ws_size < WS_NEED) return;

  hipLaunchKernelGGL(prep_kernel, dim3(896), dim3(256), 0, stream,
                     aW1, aW2, mW1, mW2, mW3, uW1, uW2, uW3, wsp);
  hipLaunchKernelGGL(actor_kernel, dim3(kB / RPB), dim3(512), 0, stream,
                     state, ub1, ub2, ub3, ab1, ab2, aW3, ab3,
                     mb1, mb2, mb3, wsp, out);
}

// Round 6
// 1406.335 us; speedup vs baseline: 3.7630x; 1.1059x over previous
//
#include <hip/hip_runtime.h>

typedef unsigned int u32;
typedef unsigned short u16;
typedef short s16x8 __attribute__((ext_vector_type(8)));
typedef float f32x4 __attribute__((ext_vector_type(4)));
typedef float f32x2 __attribute__((ext_vector_type(2)));

namespace {
constexpr int kB = 16384, kL = 20;
constexpr int RPB = 32;

// packed split-bf16 weights in d_ws (u16 elems). per (kt,n): hi[32] | lo[32]
constexpr int OFF_A1 = 0;                       // 128x256
constexpr int OFF_A2 = OFF_A1 + 128 * 256 * 2;  // 256x256
constexpr int OFF_M1 = OFF_A2 + 256 * 256 * 2;  // 128x256
constexpr int OFF_M2 = OFF_M1 + 128 * 256 * 2;  // 256x256
constexpr int OFF_M3 = OFF_M2 + 256 * 256 * 2;  // 256x64
constexpr int OFF_U1 = OFF_M3 + 256 * 64 * 2;   // 64x64
constexpr int OFF_U2 = OFF_U1 + 64 * 64 * 2;    // 128x64
constexpr int OFF_U3 = OFF_U2 + 128 * 64 * 2;   // 64x64
constexpr int PACK_ELEMS = OFF_U3 + 64 * 64 * 2;  // 458752 u16 = 896 KB
constexpr size_t WS_NEED = (size_t)PACK_ELEMS * 2;

__device__ __forceinline__ u16 f2bf(float x) {
  u32 b = __builtin_bit_cast(u32, x);
  b += 0x7FFFu + ((b >> 16) & 1u);
  return (u16)(b >> 16);
}
__device__ __forceinline__ float bf2f(u16 h) {
  return __builtin_bit_cast(float, (u32)h << 16);
}
__device__ __forceinline__ void split2(float x, u16& hi, u16& lo) {
  hi = f2bf(x);
  lo = f2bf(x - bf2f(hi));
}
__device__ __forceinline__ f32x4 mfma16(s16x8 a, s16x8 b, f32x4 c) {
  return __builtin_amdgcn_mfma_f32_16x16x32_bf16(a, b, c, 0, 0, 0);
}
__device__ __forceinline__ s16x8 ldsf(const u16* p) {
  return *reinterpret_cast<const s16x8*>(p);
}
__device__ __forceinline__ int swz(int row, int idx) { return idx ^ ((row & 7) << 3); }

__device__ __forceinline__ float fast_rcp(float x) {
#if __has_builtin(__builtin_amdgcn_rcpf)
  return __builtin_amdgcn_rcpf(x);
#else
  return 1.0f / x;
#endif
}
__device__ __forceinline__ float tfast(float x) {  // tanh, |err| ~1e-6
#if __has_builtin(__builtin_amdgcn_exp2f)
  float e = __builtin_amdgcn_exp2f(x * 2.8853900817779268f);
#else
  float e = exp2f(x * 2.8853900817779268f);
#endif
  return fmaf(-2.0f, fast_rcp(e + 1.0f), 1.0f);
}

// 256-col layers: A (hi/lo) from LDS, B frags from registers, NM=2 row tiles.
template <int KT, int LD>
__device__ __forceinline__ void mmA(const u16* __restrict__ AH, const u16* __restrict__ AL,
                                    const s16x8 (&bh)[KT], const s16x8 (&bl)[KT],
                                    int r15, int g, f32x4 (&acc)[2]) {
  #pragma unroll
  for (int kt = 0; kt < KT; ++kt) {
    #pragma unroll
    for (int m = 0; m < 2; ++m) {
      const int row = m * 16 + r15;
      const int off = swz(row, row * LD + kt * 32 + g * 8);
      s16x8 ah = ldsf(AH + off), al = ldsf(AL + off);
      acc[m] = mfma16(ah, bh[kt], acc[m]);
      acc[m] = mfma16(al, bh[kt], acc[m]);
      acc[m] = mfma16(ah, bl[kt], acc[m]);
    }
  }
}
// 64-col layers: NM=1 (mh row-half), runtime kt base (kh K-split).
template <int KT, int LD>
__device__ __forceinline__ void mmU(const u16* __restrict__ AH, const u16* __restrict__ AL,
                                    const s16x8 (&bh)[KT], const s16x8 (&bl)[KT],
                                    int ktbase, int mh, int r15, int g, f32x4& acc) {
  #pragma unroll
  for (int j = 0; j < KT; ++j) {
    const int row = mh * 16 + r15;
    const int off = swz(row, row * LD + (ktbase + j) * 32 + g * 8);
    s16x8 ah = ldsf(AH + off), al = ldsf(AL + off);
    acc = mfma16(ah, bh[j], acc);
    acc = mfma16(al, bh[j], acc);
    acc = mfma16(ah, bl[j], acc);
  }
}
}  // namespace

// ---------------- prep: pack weights into split-bf16 frag layout ----------------
__global__ __launch_bounds__(256) void prep_kernel(
    const float* __restrict__ aW1, const float* __restrict__ aW2,
    const float* __restrict__ mW1, const float* __restrict__ mW2,
    const float* __restrict__ mW3, const float* __restrict__ uW1,
    const float* __restrict__ uW2, const float* __restrict__ uW3,
    u16* __restrict__ ws) {
  const float* Ws[8] = {aW1, aW2, mW1, mW2, mW3, uW1, uW2, uW3};
  const int Ns[8]  = {256, 256, 256, 256, 64, 64, 64, 64};
  const int dst[8] = {OFF_A1, OFF_A2, OFF_M1, OFF_M2, OFF_M3, OFF_U1, OFF_U2, OFF_U3};
  const int cnt[8] = {32768, 65536, 32768, 65536, 16384, 4096, 8192, 4096};
  const int total = 229376;
  for (int e = blockIdx.x * 256 + threadIdx.x; e < total; e += gridDim.x * 256) {
    int l = 0, base = 0;
    while (e - base >= cnt[l]) { base += cnt[l]; ++l; }
    const int s = e - base, N = Ns[l];
    const int k = s / N, n = s % N;
    u16 hi, lo;
    split2(Ws[l][s], hi, lo);
    const int ob = dst[l] + ((k >> 5) * N + n) * 64 + (k & 31);
    ws[ob] = hi;
    ws[ob + 32] = lo;
  }
}

// ------- monolith: all weights in VGPRs, 16 waves, RPB=32 -------
__global__ __launch_bounds__(1024) void actor_kernel(
    const float* __restrict__ state,
    const float* __restrict__ ub1, const float* __restrict__ ub2,
    const float* __restrict__ ub3,
    const float* __restrict__ ab1, const float* __restrict__ ab2,
    const float* __restrict__ aW3, const float* __restrict__ ab3,
    const float* __restrict__ mb1, const float* __restrict__ mb2,
    const float* __restrict__ mb3,
    const u16* __restrict__ wsp, float* __restrict__ out) {
  __shared__ __align__(16) u16 lds[81920];   // 160 KB exactly
  u16* XMH = lds;            // 32x128
  u16* XML = lds + 4096;
  u16* B1H = lds + 8192;     // 32x256
  u16* B1L = lds + 16384;
  u16* B2H = lds + 24576;    // 32x256
  u16* B2L = lds + 32768;
  u16* MSGS = lds + 40960;   // 32x20x64
  // BU aliases:
  u16* XSH = B1H;            // 32x64
  u16* XSL = B1H + 2048;
  float* SMC  = reinterpret_cast<float*>(B1L);         // 32x64 f32
  float* SMC2 = reinterpret_cast<float*>(B1L) + 2048;  // 32x64 f32
  u16* H2H = B2H;            // 32x64
  u16* H2L = B2H + 2048;

  const int tid = threadIdx.x;
  const int wv = tid >> 6, lane = tid & 63;
  const int r15 = lane & 15, g = lane >> 4;
  const int nq = wv & 3, mh = (wv >> 2) & 1, kh = wv >> 3;
  const int nr = tid >> 5, np = tid & 31;     // 32 rows x 32 lanes mapping
  const int rowBase = blockIdx.x * RPB;
  const int c256 = wv * 16 + r15;             // this thread's col in 256-wide layers
  const int c64 = nq * 16 + r15;              // this thread's col in 64-wide layers

  // ---- stage ALL weight fragments into registers (once) ----
  s16x8 A1h[4], A1l[4], M1h[4], M1l[4];
  #pragma unroll
  for (int kt = 0; kt < 4; ++kt) {
    const u16* pa = wsp + OFF_A1 + (size_t)(kt * 256 + c256) * 64 + g * 8;
    A1h[kt] = ldsf(pa); A1l[kt] = ldsf(pa + 32);
    const u16* pm = wsp + OFF_M1 + (size_t)(kt * 256 + c256) * 64 + g * 8;
    M1h[kt] = ldsf(pm); M1l[kt] = ldsf(pm + 32);
  }
  s16x8 A2h[8], A2l[8], M2h[8], M2l[8];
  #pragma unroll
  for (int kt = 0; kt < 8; ++kt) {
    const u16* pa = wsp + OFF_A2 + (size_t)(kt * 256 + c256) * 64 + g * 8;
    A2h[kt] = ldsf(pa); A2l[kt] = ldsf(pa + 32);
    const u16* pm = wsp + OFF_M2 + (size_t)(kt * 256 + c256) * 64 + g * 8;
    M2h[kt] = ldsf(pm); M2l[kt] = ldsf(pm + 32);
  }
  s16x8 U1h[1], U1l[1], U3h[1], U3l[1], U2h[2], U2l[2], M3h[4], M3l[4];
  {
    const u16* p = wsp + OFF_U1 + (size_t)(kh * 64 + c64) * 64 + g * 8;
    U1h[0] = ldsf(p); U1l[0] = ldsf(p + 32);
    p = wsp + OFF_U3 + (size_t)(kh * 64 + c64) * 64 + g * 8;
    U3h[0] = ldsf(p); U3l[0] = ldsf(p + 32);
    #pragma unroll
    for (int j = 0; j < 2; ++j) {
      const u16* q = wsp + OFF_U2 + (size_t)((2 * kh + j) * 64 + c64) * 64 + g * 8;
      U2h[j] = ldsf(q); U2l[j] = ldsf(q + 32);
    }
    #pragma unroll
    for (int j = 0; j < 4; ++j) {
      const u16* q = wsp + OFF_M3 + (size_t)((4 * kh + j) * 64 + c64) * 64 + g * 8;
      M3h[j] = ldsf(q); M3l[j] = ldsf(q + 32);
    }
  }
  const float ub1v = ub1[c64], ub2v = ub2[c64], ub3v = ub3[c64], mb3v = mb3[c64];
  const float ab1v = ab1[c256], ab2v = ab2[c256], mb1v = mb1[c256], mb2v = mb2[c256];
  const float ab3v = ab3[0];
  float aw3r[8];
  #pragma unroll
  for (int j = 0; j < 8; ++j) aw3r[j] = aW3[np * 8 + j];

  // zero xm planes; stage state(t=19)
  for (int i = tid; i < 4096; i += 1024) { XMH[i] = 0; XML[i] = 0; }
  {
    f32x2 v = *reinterpret_cast<const f32x2*>(
        state + ((size_t)(rowBase + nr) * kL + (kL - 1)) * 64 + np * 2);
    u16 h0, l0, h1, l1;
    split2(v[0], h0, l0); split2(v[1], h1, l1);
    const int o = swz(nr, nr * 64 + np * 2);
    *(u32*)&XSH[o] = (u32)h0 | ((u32)h1 << 16);
    *(u32*)&XSL[o] = (u32)l0 | ((u32)l1 << 16);
  }
  __syncthreads();

  // ---------------- bottom-up: t = 19..0 ----------------
  for (int t = kL - 1; t >= 0; --t) {
    {  // s1: U1 partial -> SMCk
      f32x4 acc = {};
      mmU<1, 64>(XSH, XSL, U1h, U1l, kh, mh, r15, g, acc);
      float* SM = kh ? SMC2 : SMC;
      const float bb = kh ? 0.f : ub1v;
      #pragma unroll
      for (int i = 0; i < 4; ++i) SM[(mh * 16 + g * 4 + i) * 64 + c64] = acc[i] + bb;
    }
    __syncthreads();
    {  // s2: normalize + tanh -> XM[0:64]
      f32x2 a = *(const f32x2*)(SMC + nr * 64 + np * 2);
      f32x2 b = *(const f32x2*)(SMC2 + nr * 64 + np * 2);
      float v0 = a[0] + b[0], v1 = a[1] + b[1];
      float ss = v0 * v0 + v1 * v1;
      ss += __shfl_xor(ss, 16); ss += __shfl_xor(ss, 8);
      ss += __shfl_xor(ss, 4);  ss += __shfl_xor(ss, 2); ss += __shfl_xor(ss, 1);
      const float inv = 1.f / fmaxf(sqrtf(ss), 1e-12f);
      u16 h0, l0, h1, l1;
      split2(tfast(v0 * inv), h0, l0); split2(tfast(v1 * inv), h1, l1);
      const int o = swz(nr, nr * 128 + np * 2);
      *(u32*)&XMH[o] = (u32)h0 | ((u32)h1 << 16);
      *(u32*)&XML[o] = (u32)l0 | ((u32)l1 << 16);
    }
    __syncthreads();
    {  // s3: U2 partial -> SMCk ; fold: stage state(t-1) -> XS
      f32x4 acc = {};
      mmU<2, 128>(XMH, XML, U2h, U2l, 2 * kh, mh, r15, g, acc);
      float* SM = kh ? SMC2 : SMC;
      const float bb = kh ? 0.f : ub2v;
      #pragma unroll
      for (int i = 0; i < 4; ++i) SM[(mh * 16 + g * 4 + i) * 64 + c64] = acc[i] + bb;
      if (t > 0) {
        f32x2 v = *reinterpret_cast<const f32x2*>(
            state + ((size_t)(rowBase + nr) * kL + (t - 1)) * 64 + np * 2);
        u16 h0, l0, h1, l1;
        split2(v[0], h0, l0); split2(v[1], h1, l1);
        const int o = swz(nr, nr * 64 + np * 2);
        *(u32*)&XSH[o] = (u32)h0 | ((u32)h1 << 16);
        *(u32*)&XSL[o] = (u32)l0 | ((u32)l1 << 16);
      }
    }
    __syncthreads();
    {  // s4: h2 = tanh(SMC+SMC2) -> H2 planes
      f32x2 a = *(const f32x2*)(SMC + nr * 64 + np * 2);
      f32x2 b = *(const f32x2*)(SMC2 + nr * 64 + np * 2);
      u16 h0, l0, h1, l1;
      split2(tfast(a[0] + b[0]), h0, l0); split2(tfast(a[1] + b[1]), h1, l1);
      const int o = swz(nr, nr * 64 + np * 2);
      *(u32*)&H2H[o] = (u32)h0 | ((u32)h1 << 16);
      *(u32*)&H2L[o] = (u32)l0 | ((u32)l1 << 16);
    }
    __syncthreads();
    {  // s5: U3 partial -> SMCk
      f32x4 acc = {};
      mmU<1, 64>(H2H, H2L, U3h, U3l, kh, mh, r15, g, acc);
      float* SM = kh ? SMC2 : SMC;
      const float bb = kh ? 0.f : ub3v;
      #pragma unroll
      for (int i = 0; i < 4; ++i) SM[(mh * 16 + g * 4 + i) * 64 + c64] = acc[i] + bb;
    }
    __syncthreads();
    {  // s6: normalize -> msg (MSGS bf16) ; XM[64:] = split(tanh(msg))
      f32x2 a = *(const f32x2*)(SMC + nr * 64 + np * 2);
      f32x2 b = *(const f32x2*)(SMC2 + nr * 64 + np * 2);
      float v0 = a[0] + b[0], v1 = a[1] + b[1];
      float ss = v0 * v0 + v1 * v1;
      ss += __shfl_xor(ss, 16); ss += __shfl_xor(ss, 8);
      ss += __shfl_xor(ss, 4);  ss += __shfl_xor(ss, 2); ss += __shfl_xor(ss, 1);
      const float inv = 1.f / fmaxf(sqrtf(ss), 1e-12f);
      const float m0 = v0 * inv, m1 = v1 * inv;
      *(u32*)&MSGS[nr * (kL * 64) + t * 64 + np * 2] =
          (u32)f2bf(m0) | ((u32)f2bf(m1) << 16);
      u16 h0, l0, h1, l1;
      split2(tfast(m0), h0, l0); split2(tfast(m1), h1, l1);
      const int o = swz(nr, nr * 128 + 64 + np * 2);
      *(u32*)&XMH[o] = (u32)h0 | ((u32)h1 << 16);
      *(u32*)&XML[o] = (u32)l0 | ((u32)l1 << 16);
    }
    __syncthreads();
  }

  // ---- pre-TD: m = 0 ; xm[0:64] = tanh(MSGS[0]) ----
  {
    const int o = swz(nr, nr * 128 + 64 + np * 2);
    *(u32*)&XMH[o] = 0; *(u32*)&XML[o] = 0;
    const u32 w = *(const u32*)&MSGS[nr * (kL * 64) + np * 2];
    u16 h0, l0, h1, l1;
    split2(tfast(bf2f((u16)w)), h0, l0);
    split2(tfast(bf2f((u16)(w >> 16))), h1, l1);
    const int o2 = swz(nr, nr * 128 + np * 2);
    *(u32*)&XMH[o2] = (u32)h0 | ((u32)h1 << 16);
    *(u32*)&XML[o2] = (u32)l0 | ((u32)l1 << 16);
  }
  __syncthreads();

  // ---------------- top-down: t = 0..19 ----------------
  for (int t = 0; t < kL; ++t) {
    {  // p1: A1 -> B1 (relu)
      f32x4 acc[2] = {};
      mmA<4, 128>(XMH, XML, A1h, A1l, r15, g, acc);
      #pragma unroll
      for (int m = 0; m < 2; ++m)
        #pragma unroll
        for (int i = 0; i < 4; ++i) {
          const int row = m * 16 + g * 4 + i;
          u16 h, l;
          split2(fmaxf(acc[m][i] + ab1v, 0.f), h, l);
          const int o = swz(row, row * 256 + c256);
          B1H[o] = h; B1L[o] = l;
        }
    }
    __syncthreads();
    {  // p2: A2 -> B2 (relu)
      f32x4 acc[2] = {};
      mmA<8, 256>(B1H, B1L, A2h, A2l, r15, g, acc);
      #pragma unroll
      for (int m = 0; m < 2; ++m)
        #pragma unroll
        for (int i = 0; i < 4; ++i) {
          const int row = m * 16 + g * 4 + i;
          u16 h, l;
          split2(fmaxf(acc[m][i] + ab2v, 0.f), h, l);
          const int o = swz(row, row * 256 + c256);
          B2H[o] = h; B2L[o] = l;
        }
    }
    __syncthreads();
    {  // p3: a3 (B2 -> out) + M1 (XM -> B1, relu)
      const int o0 = swz(nr, nr * 256 + np * 8);
      s16x8 hh = ldsf(B2H + o0), ll = ldsf(B2L + o0);
      float sum = 0.f;
      #pragma unroll
      for (int j = 0; j < 8; ++j)
        sum += (bf2f((u16)hh[j]) + bf2f((u16)ll[j])) * aw3r[j];
      sum += __shfl_xor(sum, 16); sum += __shfl_xor(sum, 8);
      sum += __shfl_xor(sum, 4);  sum += __shfl_xor(sum, 2); sum += __shfl_xor(sum, 1);
      if (np == 0) out[(size_t)(rowBase + nr) * kL + t] = tfast(sum + ab3v);

      f32x4 acc[2] = {};
      mmA<4, 128>(XMH, XML, M1h, M1l, r15, g, acc);
      #pragma unroll
      for (int m = 0; m < 2; ++m)
        #pragma unroll
        for (int i = 0; i < 4; ++i) {
          const int row = m * 16 + g * 4 + i;
          u16 h, l;
          split2(fmaxf(acc[m][i] + mb1v, 0.f), h, l);
          const int o = swz(row, row * 256 + c256);
          B1H[o] = h; B1L[o] = l;
        }
    }
    __syncthreads();
    {  // p4: M2 -> B2 (relu) ; fold: xm[0:64] = tanh(MSGS[t+1])
      f32x4 acc[2] = {};
      mmA<8, 256>(B1H, B1L, M2h, M2l, r15, g, acc);
      #pragma unroll
      for (int m = 0; m < 2; ++m)
        #pragma unroll
        for (int i = 0; i < 4; ++i) {
          const int row = m * 16 + g * 4 + i;
          u16 h, l;
          split2(fmaxf(acc[m][i] + mb2v, 0.f), h, l);
          const int o = swz(row, row * 256 + c256);
          B2H[o] = h; B2L[o] = l;
        }
      if (t < kL - 1) {
        const u32 w = *(const u32*)&MSGS[nr * (kL * 64) + (t + 1) * 64 + np * 2];
        u16 h0, l0, h1, l1;
        split2(tfast(bf2f((u16)w)), h0, l0);
        split2(tfast(bf2f((u16)(w >> 16))), h1, l1);
        const int o = swz(nr, nr * 128 + np * 2);
        *(u32*)&XMH[o] = (u32)h0 | ((u32)h1 << 16);
        *(u32*)&XML[o] = (u32)l0 | ((u32)l1 << 16);
      }
    }
    __syncthreads();
    {  // p5: M3 partial (B2 ->) -> SMCk
      f32x4 acc = {};
      mmU<4, 256>(B2H, B2L, M3h, M3l, 4 * kh, mh, r15, g, acc);
      float* SM = kh ? SMC2 : SMC;
      const float bb = kh ? 0.f : mb3v;
      #pragma unroll
      for (int i = 0; i < 4; ++i) SM[(mh * 16 + g * 4 + i) * 64 + c64] = acc[i] + bb;
    }
    __syncthreads();
    {  // p6: normalize -> m ; XM[64:] = split(tanh(m))
      f32x2 a = *(const f32x2*)(SMC + nr * 64 + np * 2);
      f32x2 b = *(const f32x2*)(SMC2 + nr * 64 + np * 2);
      float v0 = a[0] + b[0], v1 = a[1] + b[1];
      float ss = v0 * v0 + v1 * v1;
      ss += __shfl_xor(ss, 16); ss += __shfl_xor(ss, 8);
      ss += __shfl_xor(ss, 4);  ss += __shfl_xor(ss, 2); ss += __shfl_xor(ss, 1);
      const float inv = 1.f / fmaxf(sqrtf(ss), 1e-12f);
      u16 h0, l0, h1, l1;
      split2(tfast(v0 * inv), h0, l0); split2(tfast(v1 * inv), h1, l1);
      const int o = swz(nr, nr * 128 + 64 + np * 2);
      *(u32*)&XMH[o] = (u32)h0 | ((u32)h1 << 16);
      *(u32*)&XML[o] = (u32)l0 | ((u32)l1 << 16);
    }
    __syncthreads();
  }
}

extern "C" void kernel_launch(void* const* d_in, const int* in_sizes, int n_in,
                              void* d_out, int out_size, void* d_ws, size_t ws_size,
                              hipStream_t stream) {
  (void)in_sizes; (void)n_in; (void)out_size;
  const float* state = (const float*)d_in[0];
  const float* uW1 = (const float*)d_in[1];
  const float* ub1 = (const float*)d_in[2];
  const float* uW2 = (const float*)d_in[3];
  const float* ub2 = (const float*)d_in[4];
  const float* uW3 = (const float*)d_in[5];
  const float* ub3 = (const float*)d_in[6];
  const float* aW1 = (const float*)d_in[7];
  const float* ab1 = (const float*)d_in[8];
  const float* aW2 = (const float*)d_in[9];
  const float* ab2 = (const float*)d_in[10];
  const float* aW3 = (const float*)d_in[11];
  const float* ab3 = (const float*)d_in[12];
  const float* mW1 = (const float*)d_in[13];
  const float* mb1 = (const float*)d_in[14];
  const float* mW2 = (const float*)d_in[15];
  const float* mb2 = (const float*)d_in[16];
  const float* mW3 = (const float*)d_in[17];
  const float* mb3 = (const float*)d_in[18];
  u16* wsp = (u16*)d_ws;
  float* out = (float*)d_out;

  if (ws_size < WS_NEED) return;

  hipLaunchKernelGGL(prep_kernel, dim3(896), dim3(256), 0, stream,
                     aW1, aW2, mW1, mW2, mW3, uW1, uW2, uW3, wsp);
  hipLaunchKernelGGL(actor_kernel, dim3(kB / RPB), dim3(1024), 0, stream,
                     state, ub1, ub2, ub3, ab1, ab2, aW3, ab3,
                     mb1, mb2, mb3, wsp, out);
}